// Round 20
// baseline (558.914 us; speedup 1.0000x reference)
//
#include <hip/hip_runtime.h>

typedef __attribute__((ext_vector_type(4))) float f32x4;
typedef __attribute__((ext_vector_type(8))) short short8;
typedef __attribute__((ext_vector_type(4))) short short4v;
typedef __attribute__((ext_vector_type(4))) int int4v;
typedef __attribute__((ext_vector_type(8))) char char8;
typedef __attribute__((ext_vector_type(16))) char char16;
typedef unsigned int uint32;

#define DEVFN static __device__ __forceinline__
#define MFMA16x16x32 __builtin_amdgcn_mfma_f32_16x16x32_bf16
#define MFMA_I8 __builtin_amdgcn_mfma_i32_16x16x64_i8

DEVFN short f2bf_rn(float f) {  // round-to-nearest-even f32->bf16 (exact for small ints)
  uint32 u = __float_as_uint(f);
  u += 0x7FFFu + ((u >> 16) & 1u);
  return (short)(u >> 16);
}
DEVFN float bf2f(short s) { return __uint_as_float(((uint32)(unsigned short)s) << 16); }
DEVFN float quant1(float v, float as) {  // int8 symmetric quant (round-half-even like jnp.round)
  return fminf(fmaxf(rintf(v / as), -128.f), 127.f);
}
DEVFN void store1(float* p, float v) { *p = v; }
DEVFN void store1(short* p, float v) { *p = f2bf_rn(v); }

DEVFN void gload_lds16(const void* g, void* l) {  // async global->LDS, 16B/lane
  __builtin_amdgcn_global_load_lds((const __attribute__((address_space(1))) void*)g,
                                   (__attribute__((address_space(3))) void*)l, 16, 0, 0);
}

// ---------------- weight repack x4: int32 (|w|<=8) -> int8, one launch ----------------
__global__ __launch_bounds__(256) void repack4_kernel(const int* __restrict__ w0,
                                                      const int* __restrict__ w1,
                                                      const int* __restrict__ w2,
                                                      const int* __restrict__ w3,
                                                      char* __restrict__ wq) {
  int which = blockIdx.x >> 8;  // 1024 blocks = 4 weights x 256 blocks
  const int* w = which == 0 ? w0 : which == 1 ? w1 : which == 2 ? w2 : w3;
  char* dst = wq + (size_t)which * 4194304;
  int base = (blockIdx.x & 255) * 1024;  // char16 units; 262144 per weight
  for (int it = 0; it < 4; it++) {
    int i = base + it * 256 + threadIdx.x;
    char16 o;
#pragma unroll
    for (int s = 0; s < 4; s++) {
      int4v v = ((const int4v*)w)[i * 4 + s];
#pragma unroll
      for (int j = 0; j < 4; j++) o[s * 4 + j] = (char)v[j];
    }
    ((char16*)dst)[i] = o;
  }
}

// ---------------- weight repack: int32 (|w|<=8) -> int8 (single) ----------------
__global__ __launch_bounds__(256) void repack_w_kernel(const int* __restrict__ w,
                                                       char* __restrict__ wq, int n16) {
  int stride = gridDim.x * blockDim.x;
  for (int i = blockIdx.x * blockDim.x + threadIdx.x; i < n16; i += stride) {
    char16 o;
#pragma unroll
    for (int s = 0; s < 4; s++) {
      int4v v = ((const int4v*)w)[i * 4 + s];
#pragma unroll
      for (int j = 0; j < 4; j++) o[s * 4 + j] = (char)v[j];
    }
    ((char16*)wq)[i] = o;
  }
}

// ------- fused activation quantize: read x once, emit all 5 int8 quantizations -------
__global__ __launch_bounds__(256) void quant5_kernel(
    const float* __restrict__ x, char* __restrict__ o_q, char* __restrict__ o_k,
    char* __restrict__ o_v, char* __restrict__ o_g, char* __restrict__ o_gk,
    const float* __restrict__ as_q, const float* __restrict__ as_k,
    const float* __restrict__ as_v, const float* __restrict__ as_g,
    const float* __restrict__ as_gk, int n8) {
  float aq = as_q[0], ak = as_k[0], av = as_v[0], ag = as_g[0], agk = as_gk[0];
  int stride = gridDim.x * blockDim.x;
  for (int i = blockIdx.x * blockDim.x + threadIdx.x; i < n8; i += stride) {
    f32x4 a = ((const f32x4*)x)[i * 2];
    f32x4 b = ((const f32x4*)x)[i * 2 + 1];
    float v[8] = {a.x, a.y, a.z, a.w, b.x, b.y, b.z, b.w};
    char8 q8, k8, v8, g8, gk8;
#pragma unroll
    for (int j = 0; j < 8; j++) {
      q8[j] = (char)(int)quant1(v[j], aq);
      k8[j] = (char)(int)quant1(v[j], ak);
      v8[j] = (char)(int)quant1(v[j], av);
      g8[j] = (char)(int)quant1(v[j], ag);
      gk8[j] = (char)(int)quant1(v[j], agk);
    }
    ((char8*)o_q)[i] = q8;
    ((char8*)o_k)[i] = k8;
    ((char8*)o_v)[i] = v8;
    ((char8*)o_g)[i] = g8;
    ((char8*)o_gk)[i] = gk8;
  }
}

// ---- i8 MFMA GEMM v5: 256x128 tile, grid 512 = 2 blocks/CU (4 waves/SIMD overlap),
// depth-2 counted-vmcnt (T4), setprio (T5). Same barrier skeleton as proven v3.
// 8 waves as 4m x 2n, wave tile 64x64 (acc[4][4]). 3 loads/thread/tile -> vmcnt(3).
template <typename OutT>
__global__ __launch_bounds__(512, 2) void gemm_i8(const char* __restrict__ A,
                                                  const char* __restrict__ W,
                                                  OutT* __restrict__ C,
                                                  const float* __restrict__ wscale,
                                                  const float* __restrict__ ascale_p) {
  const int K = 2048, N = 2048, NT = 32;
  int wg = blockIdx.x;                  // 512 blocks = 32 bm x 16 bn, 2 per CU
  int swz = (wg & 7) * 64 + (wg >> 3);  // XCD swizzle, bijective (512 % 8 == 0)
  int bm = swz >> 4, bn = swz & 15;

  __shared__ char As[2][256 * 64] __attribute__((aligned(16)));
  __shared__ char Bs[2][128 * 64] __attribute__((aligned(16)));

  int tid = threadIdx.x, lane = tid & 63, wid = tid >> 6;
  int wr = wid >> 1, wc = wid & 1;  // wave grid 4x2 -> 64x64 output per wave
  int ll = lane & 15, lh = lane >> 4;

  int4v acc[4][4];
#pragma unroll
  for (int m = 0; m < 4; m++)
#pragma unroll
    for (int n = 0; n < 4; n++) acc[m][n] = (int4v){0, 0, 0, 0};

  const char* Abase = A + (size_t)(bm * 256) * K;
  const char* Wbase = W + (size_t)(bn * 128) * K;

  // A: 256x64 (2 rounds x 512 lanes x 16B), B: 128x64 (1 round); src col pre-swizzled
#define STAGE(buf, kt)                                                                   \
  {                                                                                      \
    _Pragma("unroll") for (int i = 0; i < 2; i++) {                                      \
      int rr = i * 128 + (tid >> 2);                                                     \
      int scc = (tid & 3) ^ ((rr >> 1) & 3);                                             \
      int ub = (i * 512 + wid * 64) * 16;                                                \
      gload_lds16(Abase + (size_t)rr * K + (kt) * 64 + scc * 16, (char*)As[buf] + ub);   \
    }                                                                                    \
    {                                                                                    \
      int rr = tid >> 2;                                                                 \
      int scc = (tid & 3) ^ ((rr >> 1) & 3);                                             \
      int ub = (wid * 64) * 16;                                                          \
      gload_lds16(Wbase + (size_t)rr * K + (kt) * 64 + scc * 16, (char*)Bs[buf] + ub);   \
    }                                                                                    \
  }

  STAGE(0, 0);
  STAGE(1, 1);  // depth-2 prologue: 6 loads/thread in flight
  int cur = 0;
  for (int kt = 0; kt < NT; kt++) {
    if (kt < NT - 1)
      asm volatile("s_waitcnt vmcnt(3)" ::: "memory");
    else
      asm volatile("s_waitcnt vmcnt(0)" ::: "memory");
    __builtin_amdgcn_s_barrier();
    asm volatile("" ::: "memory");  // keep ds_reads below the barrier
    int4v af[4], bfv[4];
#pragma unroll
    for (int m = 0; m < 4; m++) {
      int row = wr * 64 + m * 16 + ll;
      af[m] = *(const int4v*)(As[cur] + row * 64 + ((lh ^ ((row >> 1) & 3)) * 16));
    }
#pragma unroll
    for (int n = 0; n < 4; n++) {
      int row = wc * 64 + n * 16 + ll;
      bfv[n] = *(const int4v*)(Bs[cur] + row * 64 + ((lh ^ ((row >> 1) & 3)) * 16));
    }
    __builtin_amdgcn_s_setprio(1);
#pragma unroll
    for (int m = 0; m < 4; m++)
#pragma unroll
      for (int n = 0; n < 4; n++) acc[m][n] = MFMA_I8(af[m], bfv[n], acc[m][n], 0, 0, 0);
    __builtin_amdgcn_s_setprio(0);
    asm volatile("" ::: "memory");  // keep ds_reads above the barrier
    __builtin_amdgcn_s_barrier();   // read-done: buffer may now be overwritten
    if (kt + 2 < NT) STAGE(cur, kt + 2);
    cur ^= 1;
  }
  float as = ascale_p[0];
#pragma unroll
  for (int n = 0; n < 4; n++) {
    int col = bn * 128 + wc * 64 + n * 16 + ll;
    float sc = as * wscale[col];
#pragma unroll
    for (int m = 0; m < 4; m++) {
      int r0 = bm * 256 + wr * 64 + m * 16 + lh * 4;
#pragma unroll
      for (int j = 0; j < 4; j++) store1(C + (size_t)(r0 + j) * N + col, (float)acc[m][n][j] * sc);
    }
  }
#undef STAGE
}

// ---- gk0 (v2, MFMA): inner[8192][16] = gk0as*w0s[n] * XQ[8192][2048]i8 x W0[16][2048]^T ----
__global__ __launch_bounds__(256) void gk0_kernel(const char* __restrict__ xq,
                                                  const int* __restrict__ w0,
                                                  const float* __restrict__ w0s,
                                                  const float* __restrict__ as_p,
                                                  float* __restrict__ inner) {
  const int K = 2048;
  __shared__ char W8[16 * 2064] __attribute__((aligned(16)));  // [n][k] int8, pitch 2064
  __shared__ char As[2][64 * 64] __attribute__((aligned(16)));

  int tid = threadIdx.x, lane = tid & 63, wid = tid >> 6;
  int ll = lane & 15, lh = lane >> 4;
  int bm = blockIdx.x;  // 128 blocks x 64 rows

#pragma unroll
  for (int i = 0; i < 32; i++) {
    int idx = i * 256 + tid;  // int4v index (8192 total)
    int4v v = ((const int4v*)w0)[idx];
    int e = idx * 4;
    char* p = W8 + (e >> 11) * 2064 + (e & 2047);
    p[0] = (char)v.x;
    p[1] = (char)v.y;
    p[2] = (char)v.z;
    p[3] = (char)v.w;
  }

  const char* Abase = xq + (size_t)(bm * 64) * K;
#define STAGEA(buf, kt)                                                              \
  {                                                                                  \
    int rr = tid >> 2, cc = tid & 3;                                                 \
    int ub = wid * 64 * 16;                                                          \
    gload_lds16(Abase + (size_t)rr * K + (kt) * 64 + cc * 16, (char*)As[buf] + ub);  \
  }

  int4v acc = (int4v){0, 0, 0, 0};
  STAGEA(0, 0);
  __syncthreads();
  int cur = 0;
  for (int kt = 0; kt < 32; kt++) {
    if (kt + 1 < 32) STAGEA(cur ^ 1, kt + 1);
    int4v bfv = *(const int4v*)(W8 + ll * 2064 + kt * 64 + lh * 16);
    int4v af = *(const int4v*)(As[cur] + (wid * 16 + ll) * 64 + lh * 16);
    acc = MFMA_I8(af, bfv, acc, 0, 0, 0);
    __syncthreads();
    cur ^= 1;
  }
  float sc = as_p[0] * w0s[ll];
  int r0 = bm * 64 + wid * 16 + lh * 4;
#pragma unroll
  for (int j = 0; j < 4; j++) inner[(size_t)(r0 + j) * 16 + ll] = (float)acc[j] * sc;
#undef STAGEA
}

// -- gk1 (v2): AB = log_sigmoid(qlinear(inner, gk1)+bias)/16 via native exp/log, f32x4 dots --
__global__ __launch_bounds__(256) void gk1_kernel(const float* __restrict__ inner,
                                                  const int* __restrict__ w1,
                                                  const float* __restrict__ w1s,
                                                  const float* __restrict__ as_p,
                                                  const float* __restrict__ bias,
                                                  float* __restrict__ glog) {
  __shared__ float xq1[8][16] __attribute__((aligned(16)));
  float as = as_p[0];
  int tid = threadIdx.x;
  int m0 = blockIdx.x * 8;
  if (tid < 128) {
    int t = tid >> 4, n = tid & 15;
    xq1[t][n] = quant1(inner[(size_t)(m0 + t) * 16 + n], as);
  }
  __syncthreads();
#pragma unroll
  for (int i = 0; i < 8; i++) {
    int j = tid + i * 256;
    const int* wr = w1 + (size_t)j * 16;
    f32x4 wv[4];
#pragma unroll
    for (int n4 = 0; n4 < 4; n4++) {
      int4v wi = *(const int4v*)(wr + n4 * 4);
      wv[n4] = (f32x4){(float)wi.x, (float)wi.y, (float)wi.z, (float)wi.w};
    }
    float sc = as * w1s[j];
    float bj = bias[j];
#pragma unroll
    for (int t = 0; t < 8; t++) {
      f32x4 a4 = {0.f, 0.f, 0.f, 0.f};
#pragma unroll
      for (int n4 = 0; n4 < 4; n4++) a4 += *(const f32x4*)&xq1[t][n4 * 4] * wv[n4];
      float raw = (a4.x + a4.y + a4.z + a4.w) * sc + bj;
      float y = __expf(-fabsf(raw));
      float ls = fminf(raw, 0.f) - __logf(1.f + y);
      glog[(size_t)(m0 + t) * 2048 + j] = ls * 0.0625f;
    }
  }
}

// ------- phase A (v3, MFMA): RAW gates, LDS prefix; U = e^{atot}(U + K''^T V) recurrence ---
__global__ __launch_bounds__(256) void phaseA_kernel(const float* __restrict__ Abuf,
                                                     const short* __restrict__ Kb,
                                                     const short* __restrict__ Vb,
                                                     short* __restrict__ U,
                                                     float* __restrict__ CT) {
  __shared__ short k2[16 * 128] __attribute__((aligned(16)));   // [s][dk], swizzled
  __shared__ short v2[16 * 128] __attribute__((aligned(16)));   // [s][dv], swizzled
  __shared__ short kt2[128 * 24] __attribute__((aligned(16)));  // [dk][s], pitch 24
  __shared__ short vt2[128 * 24] __attribute__((aligned(16)));  // [dv][s], pitch 24
  __shared__ float a_lds[16 * 136] __attribute__((aligned(16)));
  __shared__ float etot[128];

  int cid = blockIdx.x;  // [b][h][c]
  int bb = cid >> 9, h = (cid >> 5) & 15, c = cid & 31;
  size_t rowbase = ((size_t)bb * 4096 + (size_t)c * 128) * 2048 + h * 128;
  int tid = threadIdx.x, lane = tid & 63, wid = tid >> 6;
  int lh = lane >> 4, ll = lane & 15;
  int r = tid >> 4, d0 = (tid & 15) * 8;

  f32x4 acc[8][2];
#pragma unroll
  for (int tm = 0; tm < 8; tm++) {
    acc[tm][0] = (f32x4){0.f, 0.f, 0.f, 0.f};
    acc[tm][1] = (f32x4){0.f, 0.f, 0.f, 0.f};
  }
  float ct[8] = {0.f, 0.f, 0.f, 0.f, 0.f, 0.f, 0.f, 0.f};  // valid on r==15 threads

  for (int sb = 0; sb < 8; sb++) {
    __syncthreads();  // A0
    size_t ridx = rowbase + (size_t)(sb * 16 + r) * 2048 + d0;
    short8 k8 = *(const short8*)(Kb + ridx);
    short8 v8 = *(const short8*)(Vb + ridx);
    {
      f32x4 a0 = *(const f32x4*)(Abuf + ridx);
      f32x4 a1 = *(const f32x4*)(Abuf + ridx + 4);
      *(f32x4*)(a_lds + r * 136 + d0) = a0;
      *(f32x4*)(a_lds + r * 136 + d0 + 4) = a1;
    }
    __syncthreads();  // A1
    if (tid < 128) {  // per-column inclusive prefix over 16 rows
      int d = tid;
      float s = 0.f;
#pragma unroll
      for (int rr = 0; rr < 16; rr++) {
        s += a_lds[rr * 136 + d];
        a_lds[rr * 136 + d] = s;
      }
    }
    __syncthreads();  // A2
    {  // k'' = k * e^{-arel}; stage swizzled; r==15 tracks etot + chunk-total logs
      short8 ko;
#pragma unroll
      for (int j = 0; j < 8; j++) {
        float arel = a_lds[r * 136 + d0 + j];
        ko[j] = f2bf_rn(bf2f(k8[j]) * __expf(-arel));
        if (r == 15) {
          etot[d0 + j] = __expf(arel);
          ct[j] += arel;
        }
      }
      int byt = (r * 256 + d0 * 2) ^ ((r & 7) << 4);
      *(short8*)((char*)k2 + byt) = ko;
      *(short8*)((char*)v2 + byt) = v8;
    }
    __syncthreads();  // A3
    {  // transpose k2 -> kt2, v2 -> vt2
      int trow = tid >> 1, sh = (tid & 1) * 8;
      short8 tk, tv;
#pragma unroll
      for (int ss = 0; ss < 8; ss++) {
        int s = sh + ss;
        int eidx = ((s * 256 + trow * 2) ^ ((s & 7) << 4)) >> 1;
        tk[ss] = k2[eidx];
        tv[ss] = v2[eidx];
      }
      *(short8*)(kt2 + trow * 24 + sh) = tk;
      *(short8*)(vt2 + trow * 24 + sh) = tv;
    }
    __syncthreads();  // A4
    {  // U-acc update: acc = e^{atot} .* (acc + K''^T V)  (K=16 zero-extended)
      int dv0 = (2 * wid) * 16 + ll, dv1 = (2 * wid + 1) * 16 + ll;
      short8 bv0 = (short8){0, 0, 0, 0, 0, 0, 0, 0}, bv1 = bv0;
      if (lh < 2) {
        bv0 = *(const short8*)(vt2 + dv0 * 24 + lh * 8);
        bv1 = *(const short8*)(vt2 + dv1 * 24 + lh * 8);
      }
#pragma unroll
      for (int tm = 0; tm < 8; tm++) {
        short8 ak = (short8){0, 0, 0, 0, 0, 0, 0, 0};
        if (lh < 2) ak = *(const short8*)(kt2 + (tm * 16 + ll) * 24 + lh * 8);
        acc[tm][0] = MFMA16x16x32(ak, bv0, acc[tm][0], 0, 0, 0);
        acc[tm][1] = MFMA16x16x32(ak, bv1, acc[tm][1], 0, 0, 0);
      }
#pragma unroll
      for (int tm = 0; tm < 8; tm++)
#pragma unroll
        for (int j = 0; j < 4; j++) {
          float e = etot[tm * 16 + lh * 4 + j];
          acc[tm][0][j] *= e;
          acc[tm][1][j] *= e;
        }
    }
  }
  // write U as bf16 [dv][dk] (short4v fragments: 4 consecutive dk per reg group)
  size_t ub = (size_t)cid * 16384;
#pragma unroll
  for (int tm = 0; tm < 8; tm++)
#pragma unroll
    for (int tn = 0; tn < 2; tn++) {
      int dv = (2 * wid + tn) * 16 + ll;
      short4v o;
#pragma unroll
      for (int j = 0; j < 4; j++) o[j] = f2bf_rn(acc[tm][tn][j]);
      *(short4v*)(U + ub + (size_t)dv * 128 + tm * 16 + lh * 4) = o;
    }
  if (r == 15) {
#pragma unroll
    for (int j = 0; j < 8; j++) CT[(size_t)cid * 128 + d0 + j] = ct[j];
  }
}

// ------- phase B: sequential inter-chunk recurrence, U->S in place ([dv][dk] bf16) -------
__global__ __launch_bounds__(256) void phaseB_kernel(const float* __restrict__ CT,
                                                     short* __restrict__ US) {
  int bid = blockIdx.x;  // [b][h][dvb]
  int bb = bid >> 7, h = (bid >> 3) & 15, dvb = bid & 7;
  int tid = threadIdx.x;
  int dv = dvb * 16 + (tid >> 4);
  int dk0 = (tid & 15) * 8;
  f32x4 s0 = {0.f, 0.f, 0.f, 0.f}, s1 = {0.f, 0.f, 0.f, 0.f};
  size_t tb = (size_t)((bb * 16 + h) * 32) * 16384 + (size_t)dv * 128 + dk0;
  size_t ctb = (size_t)((bb * 16 + h) * 32) * 128 + dk0;
  for (int c = 0; c < 32; c++) {
    size_t off = tb + (size_t)c * 16384;
    short8 u8 = *(const short8*)(US + off);  // load U BEFORE overwrite
    f32x4 ea = *(const f32x4*)(CT + ctb + (size_t)c * 128);
    f32x4 eb = *(const f32x4*)(CT + ctb + (size_t)c * 128 + 4);
    short8 st;
    st[0] = f2bf_rn(s0.x); st[1] = f2bf_rn(s0.y); st[2] = f2bf_rn(s0.z); st[3] = f2bf_rn(s0.w);
    st[4] = f2bf_rn(s1.x); st[5] = f2bf_rn(s1.y); st[6] = f2bf_rn(s1.z); st[7] = f2bf_rn(s1.w);
    *(short8*)(US + off) = st;  // state ENTERING chunk c
#pragma unroll
    for (int j = 0; j < 4; j++) {
      s0[j] = __expf(ea[j]) * s0[j] + bf2f(u8[j]);
      s1[j] = __expf(eb[j]) * s1[j] + bf2f(u8[4 + j]);
    }
  }
}

// --- phase C (R17-proven shape: RAW gates + LDS prefix; Qb bf16) ---
__global__ __launch_bounds__(256) void phaseC_kernel(
    const float* __restrict__ Abuf, const short* __restrict__ Qb, const short* __restrict__ Kb,
    const short* __restrict__ Vb, const short* __restrict__ Gb, const short* __restrict__ S,
    const float* __restrict__ gnw, const float* __restrict__ oas_p, char* __restrict__ Oq) {
  __shared__ short st_lds[128 * 128] __attribute__((aligned(16)));  // [dv][dk], byte^((dv&7)<<4)
  __shared__ short q2[16 * 128] __attribute__((aligned(16)));       // [t][dk], byte^((t&7)<<4)
  __shared__ short k2[16 * 128] __attribute__((aligned(16)));       // [s][dk], swz
  __shared__ short v2[16 * 128] __attribute__((aligned(16)));       // [s][dv], swz
  __shared__ short kt2[128 * 24] __attribute__((aligned(16)));      // [dk][s], pitch 24
  __shared__ short vt2[128 * 24] __attribute__((aligned(16)));      // [dv][s], pitch 24
  __shared__ short p2[16 * 24] __attribute__((aligned(16)));        // [t][s], pitch 24
  __shared__ float etot[128];
  __shared__ float o_lds[16 * 136] __attribute__((aligned(16)));    // a_raw -> arel -> o rows
  __shared__ float red[16][17];

  int cid = blockIdx.x;
  int bb = cid >> 9, h = (cid >> 5) & 15, c = cid & 31;
  size_t rowbase = ((size_t)bb * 4096 + (size_t)c * 128) * 2048 + h * 128;
  int tid = threadIdx.x, lane = tid & 63, wid = tid >> 6;
  int lh = lane >> 4, ll = lane & 15;
  float oas = oas_p[0];

  // ---- init state accumulators from S (bf16 [dv][dk] global, short4v fragments) ----
  f32x4 acc[8][2];
  {
    size_t sb0 = (size_t)cid * 16384;
#pragma unroll
    for (int tm = 0; tm < 8; tm++)
#pragma unroll
      for (int tn = 0; tn < 2; tn++) {
        int dv = (2 * wid + tn) * 16 + ll;
        short4v s4 = *(const short4v*)(S + sb0 + (size_t)dv * 128 + tm * 16 + lh * 4);
        f32x4 a;
#pragma unroll
        for (int j = 0; j < 4; j++) a[j] = bf2f(s4[j]);
        acc[tm][tn] = a;
      }
  }

  int r = tid >> 4, d0 = (tid & 15) * 8;  // staging mapping
  int t_c = tid & 15, dvb = tid >> 4;     // epilogue mapping

  for (int sb = 0; sb < 8; sb++) {
    __syncthreads();  // B0
    // pass 1a: load raw a -> o_lds(a_raw); hold q,k,v in registers (q bf16)
    size_t ridx = rowbase + (size_t)(sb * 16 + r) * 2048 + d0;
    short8 q8 = *(const short8*)(Qb + ridx);
    short8 k8 = *(const short8*)(Kb + ridx);
    short8 v8 = *(const short8*)(Vb + ridx);
    {
      f32x4 a0 = *(const f32x4*)(Abuf + ridx);
      f32x4 a1 = *(const f32x4*)(Abuf + ridx + 4);
      *(f32x4*)(o_lds + r * 136 + d0) = a0;
      *(f32x4*)(o_lds + r * 136 + d0 + 4) = a1;
    }
    __syncthreads();  // B0b
    if (tid < 128) {  // per-column inclusive prefix over the 16 staged rows
      int d = tid;
      float s = 0.f;
#pragma unroll
      for (int rr = 0; rr < 16; rr++) {
        s += o_lds[rr * 136 + d];
        o_lds[rr * 136 + d] = s;
      }
    }
    __syncthreads();  // B0c
    {  // pass 1b: scale q/k by decays, write swizzled q2/k2/v2, etot
      short8 qo, ko;
#pragma unroll
      for (int j = 0; j < 8; j++) {
        float arel = o_lds[r * 136 + d0 + j];  // inclusive local prefix, <= 0
        float ep = __expf(arel);
        qo[j] = f2bf_rn(bf2f(q8[j]) * 0.08838834764831843f * ep);
        ko[j] = f2bf_rn(bf2f(k8[j]) * __expf(-arel));
        if (r == 15) etot[d0 + j] = ep;
      }
      int byt = (r * 256 + d0 * 2) ^ ((r & 7) << 4);
      *(short8*)((char*)q2 + byt) = qo;
      *(short8*)((char*)k2 + byt) = ko;
      *(short8*)((char*)v2 + byt) = v8;
    }
    __syncthreads();  // B1
    {  // pass 2: transpose k2 -> kt2, v2 -> vt2
      int trow = tid >> 1, sh = (tid & 1) * 8;
      short8 tk, tv;
#pragma unroll
      for (int ss = 0; ss < 8; ss++) {
        int s = sh + ss;
        int eidx = ((s * 256 + trow * 2) ^ ((s & 7) << 4)) >> 1;
        tk[ss] = k2[eidx];
        tv[ss] = v2[eidx];
      }
      *(short8*)(kt2 + trow * 24 + sh) = tk;
      *(short8*)(vt2 + trow * 24 + sh) = tv;
    }
    // scores: only wave0 computes & publishes masked bf16 P; all waves load aq
    short8 aq[4];
#pragma unroll
    for (int kk = 0; kk < 4; kk++) {
      int byt = (ll * 256 + (kk * 32 + lh * 8) * 2) ^ ((ll & 7) << 4);
      aq[kk] = *(const short8*)((char*)q2 + byt);
    }
    if (wid == 0) {
      f32x4 sc = {0.f, 0.f, 0.f, 0.f};
#pragma unroll
      for (int kk = 0; kk < 4; kk++) {
        int byt = (ll * 256 + (kk * 32 + lh * 8) * 2) ^ ((ll & 7) << 4);
        short8 bk = *(const short8*)((char*)k2 + byt);
        sc = MFMA16x16x32(aq[kk], bk, sc, 0, 0, 0);
      }
#pragma unroll
      for (int j = 0; j < 4; j++) {
        int t = lh * 4 + j;
        p2[t * 24 + ll] = f2bf_rn((ll <= t) ? sc[j] : 0.f);
      }
    }
    // mirror state (entering this sub-block) to st_lds as bf16
#pragma unroll
    for (int tm = 0; tm < 8; tm++)
#pragma unroll
      for (int tn = 0; tn < 2; tn++) {
        int dv = (2 * wid + tn) * 16 + ll;
        int dkb = tm * 16 + lh * 4;
        short4v pk;
#pragma unroll
        for (int j = 0; j < 4; j++) pk[j] = f2bf_rn(acc[tm][tn][j]);
        *(short4v*)((char*)st_lds + ((dv * 256 + dkb * 2) ^ ((dv & 7) << 4))) = pk;
      }
    __syncthreads();  // B2
    {  // o = q' * S + P V (MFMA), write rows to o_lds
      f32x4 oa0 = {0.f, 0.f, 0.f, 0.f}, oa1 = {0.f, 0.f, 0.f, 0.f};
      int dv0 = (2 * wid) * 16 + ll, dv1 = (2 * wid + 1) * 16 + ll;
#pragma unroll
      for (int kk = 0; kk < 4; kk++) {
        int co = (kk * 32 + lh * 8) * 2;
        short8 bs0 = *(const short8*)((char*)st_lds + ((dv0 * 256 + co) ^ ((dv0 & 7) << 4)));
        short8 bs1 = *(const short8*)((char*)st_lds + ((dv1 * 256 + co) ^ ((dv1 & 7) << 4)));
        oa0 = MFMA16x16x32(aq[kk], bs0, oa0, 0, 0, 0);
        oa1 = MFMA16x16x32(aq[kk], bs1, oa1, 0, 0, 0);
      }
      short8 ap = (short8){0, 0, 0, 0, 0, 0, 0, 0};
      short8 bv0 = ap, bv1 = ap;
      if (lh < 2) {  // K=16 zero-extended to K=32
        ap = *(const short8*)(p2 + ll * 24 + lh * 8);
        bv0 = *(const short8*)(vt2 + dv0 * 24 + lh * 8);
        bv1 = *(const short8*)(vt2 + dv1 * 24 + lh * 8);
      }
      oa0 = MFMA16x16x32(ap, bv0, oa0, 0, 0, 0);
      oa1 = MFMA16x16x32(ap, bv1, oa1, 0, 0, 0);
#pragma unroll
      for (int j = 0; j < 4; j++) {
        o_lds[(lh * 4 + j) * 136 + dv0] = oa0[j];
        o_lds[(lh * 4 + j) * 136 + dv1] = oa1[j];
      }
    }
    {  // state update: acc = e .* (acc + K''^T V)
      int dv0 = (2 * wid) * 16 + ll, dv1 = (2 * wid + 1) * 16 + ll;
      short8 bv0 = (short8){0, 0, 0, 0, 0, 0, 0, 0}, bv1 = bv0;
      if (lh < 2) {
        bv0 = *(const short8*)(vt2 + dv0 * 24 + lh * 8);
        bv1 = *(const short8*)(vt2 + dv1 * 24 + lh * 8);
      }
#pragma unroll
      for (int tm = 0; tm < 8; tm++) {
        short8 ak = (short8){0, 0, 0, 0, 0, 0, 0, 0};
        if (lh < 2) ak = *(const short8*)(kt2 + (tm * 16 + ll) * 24 + lh * 8);
        acc[tm][0] = MFMA16x16x32(ak, bv0, acc[tm][0], 0, 0, 0);
        acc[tm][1] = MFMA16x16x32(ak, bv1, acc[tm][1], 0, 0, 0);
      }
#pragma unroll
      for (int tm = 0; tm < 8; tm++)
#pragma unroll
        for (int j = 0; j < 4; j++) {
          float e = etot[tm * 16 + lh * 4 + j];  // broadcast read
          acc[tm][0][j] *= e;
          acc[tm][1][j] *= e;
        }
    }
    __syncthreads();  // B3
    {  // epilogue: RMSNorm * gnw * swish(g) -> int8 quant
      f32x4 o0 = *(const f32x4*)(o_lds + t_c * 136 + dvb * 8);
      f32x4 o1 = *(const f32x4*)(o_lds + t_c * 136 + dvb * 8 + 4);
      float ov[8] = {o0.x, o0.y, o0.z, o0.w, o1.x, o1.y, o1.z, o1.w};
      float ssq = 0.f;
#pragma unroll
      for (int j = 0; j < 8; j++) ssq += ov[j] * ov[j];
      red[t_c][dvb] = ssq;
      __syncthreads();  // B4
      float tot = 0.f;
#pragma unroll
      for (int i = 0; i < 16; i++) tot += red[t_c][i];
      float rms = rsqrtf(tot * (1.f / 128.f) + 1e-5f);
      size_t gidx = rowbase + (size_t)(sb * 16 + t_c) * 2048 + dvb * 8;
      short8 g8 = *(const short8*)(Gb + gidx);
      char8 outv;
#pragma unroll
      for (int j = 0; j < 8; j++) {
        float g = bf2f(g8[j]);
        float sw = g / (1.f + __expf(-g));
        float val = ov[j] * rms * gnw[dvb * 8 + j] * sw;
        outv[j] = (char)(int)quant1(val, oas);
      }
      *(char8*)(Oq + gidx) = outv;
    }
  }
}

extern "C" void kernel_launch(void* const* d_in, const int* in_sizes, int n_in,
                              void* d_out, int out_size, void* d_ws, size_t ws_size,
                              hipStream_t stream) {
  const float* x = (const float*)d_in[0];
  const int* qw = (const int*)d_in[1];
  const float* qws = (const float*)d_in[2];
  const float* qas = (const float*)d_in[3];
  const int* kw = (const int*)d_in[4];
  const float* kws = (const float*)d_in[5];
  const float* kas = (const float*)d_in[6];
  const int* vw = (const int*)d_in[7];
  const float* vws = (const float*)d_in[8];
  const float* vas = (const float*)d_in[9];
  const int* gw = (const int*)d_in[10];
  const float* gws = (const float*)d_in[11];
  const float* gas = (const float*)d_in[12];
  const int* ow = (const int*)d_in[13];
  const float* ows = (const float*)d_in[14];
  const float* oas = (const float*)d_in[15];
  const int* gk0w = (const int*)d_in[16];
  const float* gk0ws = (const float*)d_in[17];
  const float* gk0as = (const float*)d_in[18];
  const int* gk1w = (const int*)d_in[19];
  const float* gk1ws = (const float*)d_in[20];
  const float* gk1as = (const float*)d_in[21];
  const float* gk1b = (const float*)d_in[22];
  const float* gnw = (const float*)d_in[23];

  const size_t NEEDED = 234881024ull;  // 224 MiB
  if (ws_size < NEEDED) return;

  char* ws = (char*)d_ws;
  char* WB = ws;
  char* XQq = ws + 16777216ull;
  short* KB = (short*)(ws + 33554432ull);
  short* VB = (short*)(ws + 67108864ull);
  short* GB = (short*)(ws + 100663296ull);
  char* XQk = ws + 134217728ull;
  char* XQv = ws + 150994944ull;
  char* XQg = ws + 167772160ull;
  char* XQgk = ws + 184549376ull;
  float* AB = (float*)(ws + 134217728ull);  // written by gk1 AFTER XQk..XQgk consumed
  short* US = (short*)(ws + 201326592ull);
  float* INNER = (float*)(ws + 201326592ull);
  char* OW = ws + 201326592ull;
  float* CT = (float*)ws;     // 512 KB, reuses dead weight region (phaseA onward)
  short* QB = (short*)d_out;  // q stored bf16, borrowing d_out until phaseC consumes it
  char* OQ = XQq;             // OQ reuses XQq slot (dead after q-GEMM)

  // 1. repack q,k,v,g weights (int32 -> int8), single fused launch
  repack4_kernel<<<1024, 256, 0, stream>>>(qw, kw, vw, gw, WB);

  // 2. fused activation quant (read x once, 5 int8 outputs)
  quant5_kernel<<<2048, 256, 0, stream>>>(x, XQq, XQk, XQv, XQg, XQgk, qas, kas, vas, gas,
                                          gk0as, 2097152);

  // 3. projections (256x128-tile i8-MFMA GEMMs, grid 512 = 2 blocks/CU); q bf16
  gemm_i8<short><<<512, 512, 0, stream>>>(XQq, WB + 0ull * 4194304, QB, qws, qas);
  gemm_i8<short><<<512, 512, 0, stream>>>(XQk, WB + 1ull * 4194304, KB, kws, kas);
  gemm_i8<short><<<512, 512, 0, stream>>>(XQv, WB + 2ull * 4194304, VB, vws, vas);
  gemm_i8<short><<<512, 512, 0, stream>>>(XQg, WB + 3ull * 4194304, GB, gws, gas);

  // 4. gk path: i8-MFMA gk0, then gk1 (RAW log-gates) -> AB
  gk0_kernel<<<128, 256, 0, stream>>>(XQgk, gk0w, gk0ws, gk0as, INNER);
  gk1_kernel<<<1024, 256, 0, stream>>>(INNER, gk1w, gk1ws, gk1as, gk1b, AB);

  // 5. chunked GLA scan (CT overwrites dead q/k/v/g weights)
  phaseA_kernel<<<1024, 256, 0, stream>>>(AB, KB, VB, US, CT);
  phaseB_kernel<<<256, 256, 0, stream>>>(CT, US);
  phaseC_kernel<<<1024, 256, 0, stream>>>(AB, QB, KB, VB, GB, US, gnw, oas, OQ);

  // 6. output projection (OW repacked into dead US region)
  repack_w_kernel<<<1024, 256, 0, stream>>>(ow, OW, 262144);
  gemm_i8<float><<<512, 512, 0, stream>>>(OQ, OW, (float*)d_out, ows, oas);
}

// Round 21
// 547.243 us; speedup vs baseline: 1.0213x; 1.0213x over previous
//
#include <hip/hip_runtime.h>

typedef __attribute__((ext_vector_type(4))) float f32x4;
typedef __attribute__((ext_vector_type(8))) short short8;
typedef __attribute__((ext_vector_type(4))) short short4v;
typedef __attribute__((ext_vector_type(4))) int int4v;
typedef __attribute__((ext_vector_type(8))) char char8;
typedef __attribute__((ext_vector_type(16))) char char16;
typedef unsigned int uint32;

#define DEVFN static __device__ __forceinline__
#define MFMA16x16x32 __builtin_amdgcn_mfma_f32_16x16x32_bf16
#define MFMA_I8 __builtin_amdgcn_mfma_i32_16x16x64_i8

DEVFN short f2bf_rn(float f) {  // round-to-nearest-even f32->bf16 (exact for small ints)
  uint32 u = __float_as_uint(f);
  u += 0x7FFFu + ((u >> 16) & 1u);
  return (short)(u >> 16);
}
DEVFN float bf2f(short s) { return __uint_as_float(((uint32)(unsigned short)s) << 16); }
DEVFN float quant1(float v, float as) {  // int8 symmetric quant (round-half-even like jnp.round)
  return fminf(fmaxf(rintf(v / as), -128.f), 127.f);
}
DEVFN void store1(float* p, float v) { *p = v; }
DEVFN void store1(short* p, float v) { *p = f2bf_rn(v); }

DEVFN void gload_lds16(const void* g, void* l) {  // async global->LDS, 16B/lane
  __builtin_amdgcn_global_load_lds((const __attribute__((address_space(1))) void*)g,
                                   (__attribute__((address_space(3))) void*)l, 16, 0, 0);
}

// ---------------- weight repack x4: int32 (|w|<=8) -> int8, one launch ----------------
__global__ __launch_bounds__(256) void repack4_kernel(const int* __restrict__ w0,
                                                      const int* __restrict__ w1,
                                                      const int* __restrict__ w2,
                                                      const int* __restrict__ w3,
                                                      char* __restrict__ wq) {
  int which = blockIdx.x >> 8;  // 1024 blocks = 4 weights x 256 blocks
  const int* w = which == 0 ? w0 : which == 1 ? w1 : which == 2 ? w2 : w3;
  char* dst = wq + (size_t)which * 4194304;
  int base = (blockIdx.x & 255) * 1024;  // char16 units; 262144 per weight
  for (int it = 0; it < 4; it++) {
    int i = base + it * 256 + threadIdx.x;
    char16 o;
#pragma unroll
    for (int s = 0; s < 4; s++) {
      int4v v = ((const int4v*)w)[i * 4 + s];
#pragma unroll
      for (int j = 0; j < 4; j++) o[s * 4 + j] = (char)v[j];
    }
    ((char16*)dst)[i] = o;
  }
}

// ---------------- weight repack: int32 (|w|<=8) -> int8 (single) ----------------
__global__ __launch_bounds__(256) void repack_w_kernel(const int* __restrict__ w,
                                                       char* __restrict__ wq, int n16) {
  int stride = gridDim.x * blockDim.x;
  for (int i = blockIdx.x * blockDim.x + threadIdx.x; i < n16; i += stride) {
    char16 o;
#pragma unroll
    for (int s = 0; s < 4; s++) {
      int4v v = ((const int4v*)w)[i * 4 + s];
#pragma unroll
      for (int j = 0; j < 4; j++) o[s * 4 + j] = (char)v[j];
    }
    ((char16*)wq)[i] = o;
  }
}

// ------- fused activation quantize: read x once, emit all 5 int8 quantizations -------
__global__ __launch_bounds__(256) void quant5_kernel(
    const float* __restrict__ x, char* __restrict__ o_q, char* __restrict__ o_k,
    char* __restrict__ o_v, char* __restrict__ o_g, char* __restrict__ o_gk,
    const float* __restrict__ as_q, const float* __restrict__ as_k,
    const float* __restrict__ as_v, const float* __restrict__ as_g,
    const float* __restrict__ as_gk, int n8) {
  float aq = as_q[0], ak = as_k[0], av = as_v[0], ag = as_g[0], agk = as_gk[0];
  int stride = gridDim.x * blockDim.x;
  for (int i = blockIdx.x * blockDim.x + threadIdx.x; i < n8; i += stride) {
    f32x4 a = ((const f32x4*)x)[i * 2];
    f32x4 b = ((const f32x4*)x)[i * 2 + 1];
    float v[8] = {a.x, a.y, a.z, a.w, b.x, b.y, b.z, b.w};
    char8 q8, k8, v8, g8, gk8;
#pragma unroll
    for (int j = 0; j < 8; j++) {
      q8[j] = (char)(int)quant1(v[j], aq);
      k8[j] = (char)(int)quant1(v[j], ak);
      v8[j] = (char)(int)quant1(v[j], av);
      g8[j] = (char)(int)quant1(v[j], ag);
      gk8[j] = (char)(int)quant1(v[j], agk);
    }
    ((char8*)o_q)[i] = q8;
    ((char8*)o_k)[i] = k8;
    ((char8*)o_v)[i] = v8;
    ((char8*)o_g)[i] = g8;
    ((char8*)o_gk)[i] = gk8;
  }
}

// ---- i8 MFMA GEMM worker (v3-proven): 256^2 tile, depth-2 counted-vmcnt, setprio ----
template <typename OutT>
DEVFN void gemm_body(int wg, const char* __restrict__ A, const char* __restrict__ W,
                     OutT* __restrict__ C, const float* __restrict__ wscale,
                     const float* __restrict__ ascale_p, char* As0, char* As1, char* Bs0,
                     char* Bs1) {
  const int K = 2048, N = 2048, NT = 32;
  int swz = (wg & 7) * 32 + (wg >> 3);  // XCD swizzle, bijective (256 % 8 == 0)
  int bm = swz >> 3, bn = swz & 7;

  char* As[2] = {As0, As1};
  char* Bs[2] = {Bs0, Bs1};

  int tid = threadIdx.x, lane = tid & 63, wid = tid >> 6;
  int wr = wid >> 2, wc = wid & 3;  // wave grid 2x4 -> 128x64 output per wave
  int ll = lane & 15, lh = lane >> 4;

  int4v acc[8][4];
#pragma unroll
  for (int m = 0; m < 8; m++)
#pragma unroll
    for (int n = 0; n < 4; n++) acc[m][n] = (int4v){0, 0, 0, 0};

  const char* Abase = A + (size_t)(bm * 256) * K;
  const char* Wbase = W + (size_t)(bn * 256) * K;

#define STAGE(buf, kt)                                                                   \
  {                                                                                      \
    _Pragma("unroll") for (int i = 0; i < 2; i++) {                                      \
      int rr = i * 128 + (tid >> 2);                                                     \
      int scc = (tid & 3) ^ ((rr >> 1) & 3);                                             \
      int ub = (i * 512 + wid * 64) * 16;                                                \
      gload_lds16(Abase + (size_t)rr * K + (kt) * 64 + scc * 16, As[buf] + ub);          \
      gload_lds16(Wbase + (size_t)rr * K + (kt) * 64 + scc * 16, Bs[buf] + ub);          \
    }                                                                                    \
  }

  STAGE(0, 0);
  STAGE(1, 1);  // depth-2 prologue: 8 loads/thread in flight
  int cur = 0;
  for (int kt = 0; kt < NT; kt++) {
    if (kt < NT - 1)
      asm volatile("s_waitcnt vmcnt(4)" ::: "memory");
    else
      asm volatile("s_waitcnt vmcnt(0)" ::: "memory");
    __builtin_amdgcn_s_barrier();
    asm volatile("" ::: "memory");  // keep ds_reads below the barrier
    int4v af[8], bfv[4];
#pragma unroll
    for (int m = 0; m < 8; m++) {
      int row = wr * 128 + m * 16 + ll;
      af[m] = *(const int4v*)(As[cur] + row * 64 + ((lh ^ ((row >> 1) & 3)) * 16));
    }
#pragma unroll
    for (int n = 0; n < 4; n++) {
      int row = wc * 64 + n * 16 + ll;
      bfv[n] = *(const int4v*)(Bs[cur] + row * 64 + ((lh ^ ((row >> 1) & 3)) * 16));
    }
    __builtin_amdgcn_s_setprio(1);
#pragma unroll
    for (int m = 0; m < 8; m++)
#pragma unroll
      for (int n = 0; n < 4; n++) acc[m][n] = MFMA_I8(af[m], bfv[n], acc[m][n], 0, 0, 0);
    __builtin_amdgcn_s_setprio(0);
    asm volatile("" ::: "memory");  // keep ds_reads above the barrier
    __builtin_amdgcn_s_barrier();   // read-done: buffer may now be overwritten
    if (kt + 2 < NT) STAGE(cur, kt + 2);
    cur ^= 1;
  }
  float as = ascale_p[0];
#pragma unroll
  for (int n = 0; n < 4; n++) {
    int col = bn * 256 + wc * 64 + n * 16 + ll;
    float sc = as * wscale[col];
#pragma unroll
    for (int m = 0; m < 8; m++) {
      int r0 = bm * 256 + wr * 128 + m * 16 + lh * 4;
#pragma unroll
      for (int j = 0; j < 4; j++) store1(C + (size_t)(r0 + j) * N + col, (float)acc[m][n][j] * sc);
    }
  }
#undef STAGE
}

// batched: 4 projection GEMMs (q,k,v,g) in one launch; blockIdx>>8 selects the GEMM
__global__ __launch_bounds__(512, 2) void gemm4_i8(
    const char* __restrict__ A0, const char* __restrict__ A1, const char* __restrict__ A2,
    const char* __restrict__ A3, const char* __restrict__ Wall, short* __restrict__ C0,
    short* __restrict__ C1, short* __restrict__ C2, short* __restrict__ C3,
    const float* __restrict__ ws0, const float* __restrict__ ws1,
    const float* __restrict__ ws2, const float* __restrict__ ws3,
    const float* __restrict__ as0, const float* __restrict__ as1,
    const float* __restrict__ as2, const float* __restrict__ as3) {
  __shared__ char As0[256 * 64] __attribute__((aligned(16)));
  __shared__ char As1[256 * 64] __attribute__((aligned(16)));
  __shared__ char Bs0[256 * 64] __attribute__((aligned(16)));
  __shared__ char Bs1[256 * 64] __attribute__((aligned(16)));
  int sub = blockIdx.x >> 8, wg = blockIdx.x & 255;
  const char* A = sub == 0 ? A0 : sub == 1 ? A1 : sub == 2 ? A2 : A3;
  short* C = sub == 0 ? C0 : sub == 1 ? C1 : sub == 2 ? C2 : C3;
  const float* wsc = sub == 0 ? ws0 : sub == 1 ? ws1 : sub == 2 ? ws2 : ws3;
  const float* asc = sub == 0 ? as0 : sub == 1 ? as1 : sub == 2 ? as2 : as3;
  gemm_body<short>(wg, A, Wall + (size_t)sub * 4194304, C, wsc, asc, As0, As1, Bs0, Bs1);
}

// single GEMM (o-projection, float out)
__global__ __launch_bounds__(512, 2) void gemm_i8(const char* __restrict__ A,
                                                  const char* __restrict__ W,
                                                  float* __restrict__ C,
                                                  const float* __restrict__ wscale,
                                                  const float* __restrict__ ascale_p) {
  __shared__ char As0[256 * 64] __attribute__((aligned(16)));
  __shared__ char As1[256 * 64] __attribute__((aligned(16)));
  __shared__ char Bs0[256 * 64] __attribute__((aligned(16)));
  __shared__ char Bs1[256 * 64] __attribute__((aligned(16)));
  gemm_body<float>(blockIdx.x, A, W, C, wscale, ascale_p, As0, As1, Bs0, Bs1);
}

// ---- gk0 (v2, MFMA): inner[8192][16] = gk0as*w0s[n] * XQ[8192][2048]i8 x W0[16][2048]^T ----
__global__ __launch_bounds__(256) void gk0_kernel(const char* __restrict__ xq,
                                                  const int* __restrict__ w0,
                                                  const float* __restrict__ w0s,
                                                  const float* __restrict__ as_p,
                                                  float* __restrict__ inner) {
  const int K = 2048;
  __shared__ char W8[16 * 2064] __attribute__((aligned(16)));  // [n][k] int8, pitch 2064
  __shared__ char As[2][64 * 64] __attribute__((aligned(16)));

  int tid = threadIdx.x, lane = tid & 63, wid = tid >> 6;
  int ll = lane & 15, lh = lane >> 4;
  int bm = blockIdx.x;  // 128 blocks x 64 rows

#pragma unroll
  for (int i = 0; i < 32; i++) {
    int idx = i * 256 + tid;  // int4v index (8192 total)
    int4v v = ((const int4v*)w0)[idx];
    int e = idx * 4;
    char* p = W8 + (e >> 11) * 2064 + (e & 2047);
    p[0] = (char)v.x;
    p[1] = (char)v.y;
    p[2] = (char)v.z;
    p[3] = (char)v.w;
  }

  const char* Abase = xq + (size_t)(bm * 64) * K;
#define STAGEA(buf, kt)                                                              \
  {                                                                                  \
    int rr = tid >> 2, cc = tid & 3;                                                 \
    int ub = wid * 64 * 16;                                                          \
    gload_lds16(Abase + (size_t)rr * K + (kt) * 64 + cc * 16, (char*)As[buf] + ub);  \
  }

  int4v acc = (int4v){0, 0, 0, 0};
  STAGEA(0, 0);
  __syncthreads();
  int cur = 0;
  for (int kt = 0; kt < 32; kt++) {
    if (kt + 1 < 32) STAGEA(cur ^ 1, kt + 1);
    int4v bfv = *(const int4v*)(W8 + ll * 2064 + kt * 64 + lh * 16);
    int4v af = *(const int4v*)(As[cur] + (wid * 16 + ll) * 64 + lh * 16);
    acc = MFMA_I8(af, bfv, acc, 0, 0, 0);
    __syncthreads();
    cur ^= 1;
  }
  float sc = as_p[0] * w0s[ll];
  int r0 = bm * 64 + wid * 16 + lh * 4;
#pragma unroll
  for (int j = 0; j < 4; j++) inner[(size_t)(r0 + j) * 16 + ll] = (float)acc[j] * sc;
#undef STAGEA
}

// -- gk1 (v2): AB = log_sigmoid(qlinear(inner, gk1)+bias)/16 via native exp/log, f32x4 dots --
__global__ __launch_bounds__(256) void gk1_kernel(const float* __restrict__ inner,
                                                  const int* __restrict__ w1,
                                                  const float* __restrict__ w1s,
                                                  const float* __restrict__ as_p,
                                                  const float* __restrict__ bias,
                                                  float* __restrict__ glog) {
  __shared__ float xq1[8][16] __attribute__((aligned(16)));
  float as = as_p[0];
  int tid = threadIdx.x;
  int m0 = blockIdx.x * 8;
  if (tid < 128) {
    int t = tid >> 4, n = tid & 15;
    xq1[t][n] = quant1(inner[(size_t)(m0 + t) * 16 + n], as);
  }
  __syncthreads();
#pragma unroll
  for (int i = 0; i < 8; i++) {
    int j = tid + i * 256;
    const int* wr = w1 + (size_t)j * 16;
    f32x4 wv[4];
#pragma unroll
    for (int n4 = 0; n4 < 4; n4++) {
      int4v wi = *(const int4v*)(wr + n4 * 4);
      wv[n4] = (f32x4){(float)wi.x, (float)wi.y, (float)wi.z, (float)wi.w};
    }
    float sc = as * w1s[j];
    float bj = bias[j];
#pragma unroll
    for (int t = 0; t < 8; t++) {
      f32x4 a4 = {0.f, 0.f, 0.f, 0.f};
#pragma unroll
      for (int n4 = 0; n4 < 4; n4++) a4 += *(const f32x4*)&xq1[t][n4 * 4] * wv[n4];
      float raw = (a4.x + a4.y + a4.z + a4.w) * sc + bj;
      float y = __expf(-fabsf(raw));
      float ls = fminf(raw, 0.f) - __logf(1.f + y);
      glog[(size_t)(m0 + t) * 2048 + j] = ls * 0.0625f;
    }
  }
}

// ------- phase A (v3, MFMA): RAW gates, LDS prefix; U = e^{atot}(U + K''^T V) recurrence ---
__global__ __launch_bounds__(256) void phaseA_kernel(const float* __restrict__ Abuf,
                                                     const short* __restrict__ Kb,
                                                     const short* __restrict__ Vb,
                                                     short* __restrict__ U,
                                                     float* __restrict__ CT) {
  __shared__ short k2[16 * 128] __attribute__((aligned(16)));   // [s][dk], swizzled
  __shared__ short v2[16 * 128] __attribute__((aligned(16)));   // [s][dv], swizzled
  __shared__ short kt2[128 * 24] __attribute__((aligned(16)));  // [dk][s], pitch 24
  __shared__ short vt2[128 * 24] __attribute__((aligned(16)));  // [dv][s], pitch 24
  __shared__ float a_lds[16 * 136] __attribute__((aligned(16)));
  __shared__ float etot[128];

  int cid = blockIdx.x;  // [b][h][c]
  int bb = cid >> 9, h = (cid >> 5) & 15, c = cid & 31;
  size_t rowbase = ((size_t)bb * 4096 + (size_t)c * 128) * 2048 + h * 128;
  int tid = threadIdx.x, lane = tid & 63, wid = tid >> 6;
  int lh = lane >> 4, ll = lane & 15;
  int r = tid >> 4, d0 = (tid & 15) * 8;

  f32x4 acc[8][2];
#pragma unroll
  for (int tm = 0; tm < 8; tm++) {
    acc[tm][0] = (f32x4){0.f, 0.f, 0.f, 0.f};
    acc[tm][1] = (f32x4){0.f, 0.f, 0.f, 0.f};
  }
  float ct[8] = {0.f, 0.f, 0.f, 0.f, 0.f, 0.f, 0.f, 0.f};  // valid on r==15 threads

  for (int sb = 0; sb < 8; sb++) {
    __syncthreads();  // A0
    size_t ridx = rowbase + (size_t)(sb * 16 + r) * 2048 + d0;
    short8 k8 = *(const short8*)(Kb + ridx);
    short8 v8 = *(const short8*)(Vb + ridx);
    {
      f32x4 a0 = *(const f32x4*)(Abuf + ridx);
      f32x4 a1 = *(const f32x4*)(Abuf + ridx + 4);
      *(f32x4*)(a_lds + r * 136 + d0) = a0;
      *(f32x4*)(a_lds + r * 136 + d0 + 4) = a1;
    }
    __syncthreads();  // A1
    if (tid < 128) {  // per-column inclusive prefix over 16 rows
      int d = tid;
      float s = 0.f;
#pragma unroll
      for (int rr = 0; rr < 16; rr++) {
        s += a_lds[rr * 136 + d];
        a_lds[rr * 136 + d] = s;
      }
    }
    __syncthreads();  // A2
    {  // k'' = k * e^{-arel}; stage swizzled; r==15 tracks etot + chunk-total logs
      short8 ko;
#pragma unroll
      for (int j = 0; j < 8; j++) {
        float arel = a_lds[r * 136 + d0 + j];
        ko[j] = f2bf_rn(bf2f(k8[j]) * __expf(-arel));
        if (r == 15) {
          etot[d0 + j] = __expf(arel);
          ct[j] += arel;
        }
      }
      int byt = (r * 256 + d0 * 2) ^ ((r & 7) << 4);
      *(short8*)((char*)k2 + byt) = ko;
      *(short8*)((char*)v2 + byt) = v8;
    }
    __syncthreads();  // A3
    {  // transpose k2 -> kt2, v2 -> vt2
      int trow = tid >> 1, sh = (tid & 1) * 8;
      short8 tk, tv;
#pragma unroll
      for (int ss = 0; ss < 8; ss++) {
        int s = sh + ss;
        int eidx = ((s * 256 + trow * 2) ^ ((s & 7) << 4)) >> 1;
        tk[ss] = k2[eidx];
        tv[ss] = v2[eidx];
      }
      *(short8*)(kt2 + trow * 24 + sh) = tk;
      *(short8*)(vt2 + trow * 24 + sh) = tv;
    }
    __syncthreads();  // A4
    {  // U-acc update: acc = e^{atot} .* (acc + K''^T V)  (K=16 zero-extended)
      int dv0 = (2 * wid) * 16 + ll, dv1 = (2 * wid + 1) * 16 + ll;
      short8 bv0 = (short8){0, 0, 0, 0, 0, 0, 0, 0}, bv1 = bv0;
      if (lh < 2) {
        bv0 = *(const short8*)(vt2 + dv0 * 24 + lh * 8);
        bv1 = *(const short8*)(vt2 + dv1 * 24 + lh * 8);
      }
#pragma unroll
      for (int tm = 0; tm < 8; tm++) {
        short8 ak = (short8){0, 0, 0, 0, 0, 0, 0, 0};
        if (lh < 2) ak = *(const short8*)(kt2 + (tm * 16 + ll) * 24 + lh * 8);
        acc[tm][0] = MFMA16x16x32(ak, bv0, acc[tm][0], 0, 0, 0);
        acc[tm][1] = MFMA16x16x32(ak, bv1, acc[tm][1], 0, 0, 0);
      }
#pragma unroll
      for (int tm = 0; tm < 8; tm++)
#pragma unroll
        for (int j = 0; j < 4; j++) {
          float e = etot[tm * 16 + lh * 4 + j];
          acc[tm][0][j] *= e;
          acc[tm][1][j] *= e;
        }
    }
  }
  // write U as bf16 [dv][dk] (short4v fragments: 4 consecutive dk per reg group)
  size_t ub = (size_t)cid * 16384;
#pragma unroll
  for (int tm = 0; tm < 8; tm++)
#pragma unroll
    for (int tn = 0; tn < 2; tn++) {
      int dv = (2 * wid + tn) * 16 + ll;
      short4v o;
#pragma unroll
      for (int j = 0; j < 4; j++) o[j] = f2bf_rn(acc[tm][tn][j]);
      *(short4v*)(U + ub + (size_t)dv * 128 + tm * 16 + lh * 4) = o;
    }
  if (r == 15) {
#pragma unroll
    for (int j = 0; j < 8; j++) CT[(size_t)cid * 128 + d0 + j] = ct[j];
  }
}

// ------- phase B: sequential inter-chunk recurrence, U->S in place ([dv][dk] bf16) -------
__global__ __launch_bounds__(256) void phaseB_kernel(const float* __restrict__ CT,
                                                     short* __restrict__ US) {
  int bid = blockIdx.x;  // [b][h][dvb]
  int bb = bid >> 7, h = (bid >> 3) & 15, dvb = bid & 7;
  int tid = threadIdx.x;
  int dv = dvb * 16 + (tid >> 4);
  int dk0 = (tid & 15) * 8;
  f32x4 s0 = {0.f, 0.f, 0.f, 0.f}, s1 = {0.f, 0.f, 0.f, 0.f};
  size_t tb = (size_t)((bb * 16 + h) * 32) * 16384 + (size_t)dv * 128 + dk0;
  size_t ctb = (size_t)((bb * 16 + h) * 32) * 128 + dk0;
  for (int c = 0; c < 32; c++) {
    size_t off = tb + (size_t)c * 16384;
    short8 u8 = *(const short8*)(US + off);  // load U BEFORE overwrite
    f32x4 ea = *(const f32x4*)(CT + ctb + (size_t)c * 128);
    f32x4 eb = *(const f32x4*)(CT + ctb + (size_t)c * 128 + 4);
    short8 st;
    st[0] = f2bf_rn(s0.x); st[1] = f2bf_rn(s0.y); st[2] = f2bf_rn(s0.z); st[3] = f2bf_rn(s0.w);
    st[4] = f2bf_rn(s1.x); st[5] = f2bf_rn(s1.y); st[6] = f2bf_rn(s1.z); st[7] = f2bf_rn(s1.w);
    *(short8*)(US + off) = st;  // state ENTERING chunk c
#pragma unroll
    for (int j = 0; j < 4; j++) {
      s0[j] = __expf(ea[j]) * s0[j] + bf2f(u8[j]);
      s1[j] = __expf(eb[j]) * s1[j] + bf2f(u8[4 + j]);
    }
  }
}

// --- phase C (R17-proven shape: RAW gates + LDS prefix; Qb bf16) ---
__global__ __launch_bounds__(256) void phaseC_kernel(
    const float* __restrict__ Abuf, const short* __restrict__ Qb, const short* __restrict__ Kb,
    const short* __restrict__ Vb, const short* __restrict__ Gb, const short* __restrict__ S,
    const float* __restrict__ gnw, const float* __restrict__ oas_p, char* __restrict__ Oq) {
  __shared__ short st_lds[128 * 128] __attribute__((aligned(16)));  // [dv][dk], byte^((dv&7)<<4)
  __shared__ short q2[16 * 128] __attribute__((aligned(16)));       // [t][dk], byte^((t&7)<<4)
  __shared__ short k2[16 * 128] __attribute__((aligned(16)));       // [s][dk], swz
  __shared__ short v2[16 * 128] __attribute__((aligned(16)));       // [s][dv], swz
  __shared__ short kt2[128 * 24] __attribute__((aligned(16)));      // [dk][s], pitch 24
  __shared__ short vt2[128 * 24] __attribute__((aligned(16)));      // [dv][s], pitch 24
  __shared__ short p2[16 * 24] __attribute__((aligned(16)));        // [t][s], pitch 24
  __shared__ float etot[128];
  __shared__ float o_lds[16 * 136] __attribute__((aligned(16)));    // a_raw -> arel -> o rows
  __shared__ float red[16][17];

  int cid = blockIdx.x;
  int bb = cid >> 9, h = (cid >> 5) & 15, c = cid & 31;
  size_t rowbase = ((size_t)bb * 4096 + (size_t)c * 128) * 2048 + h * 128;
  int tid = threadIdx.x, lane = tid & 63, wid = tid >> 6;
  int lh = lane >> 4, ll = lane & 15;
  float oas = oas_p[0];

  // ---- init state accumulators from S (bf16 [dv][dk] global, short4v fragments) ----
  f32x4 acc[8][2];
  {
    size_t sb0 = (size_t)cid * 16384;
#pragma unroll
    for (int tm = 0; tm < 8; tm++)
#pragma unroll
      for (int tn = 0; tn < 2; tn++) {
        int dv = (2 * wid + tn) * 16 + ll;
        short4v s4 = *(const short4v*)(S + sb0 + (size_t)dv * 128 + tm * 16 + lh * 4);
        f32x4 a;
#pragma unroll
        for (int j = 0; j < 4; j++) a[j] = bf2f(s4[j]);
        acc[tm][tn] = a;
      }
  }

  int r = tid >> 4, d0 = (tid & 15) * 8;  // staging mapping
  int t_c = tid & 15, dvb = tid >> 4;     // epilogue mapping

  for (int sb = 0; sb < 8; sb++) {
    __syncthreads();  // B0
    // pass 1a: load raw a -> o_lds(a_raw); hold q,k,v in registers (q bf16)
    size_t ridx = rowbase + (size_t)(sb * 16 + r) * 2048 + d0;
    short8 q8 = *(const short8*)(Qb + ridx);
    short8 k8 = *(const short8*)(Kb + ridx);
    short8 v8 = *(const short8*)(Vb + ridx);
    {
      f32x4 a0 = *(const f32x4*)(Abuf + ridx);
      f32x4 a1 = *(const f32x4*)(Abuf + ridx + 4);
      *(f32x4*)(o_lds + r * 136 + d0) = a0;
      *(f32x4*)(o_lds + r * 136 + d0 + 4) = a1;
    }
    __syncthreads();  // B0b
    if (tid < 128) {  // per-column inclusive prefix over the 16 staged rows
      int d = tid;
      float s = 0.f;
#pragma unroll
      for (int rr = 0; rr < 16; rr++) {
        s += o_lds[rr * 136 + d];
        o_lds[rr * 136 + d] = s;
      }
    }
    __syncthreads();  // B0c
    {  // pass 1b: scale q/k by decays, write swizzled q2/k2/v2, etot
      short8 qo, ko;
#pragma unroll
      for (int j = 0; j < 8; j++) {
        float arel = o_lds[r * 136 + d0 + j];  // inclusive local prefix, <= 0
        float ep = __expf(arel);
        qo[j] = f2bf_rn(bf2f(q8[j]) * 0.08838834764831843f * ep);
        ko[j] = f2bf_rn(bf2f(k8[j]) * __expf(-arel));
        if (r == 15) etot[d0 + j] = ep;
      }
      int byt = (r * 256 + d0 * 2) ^ ((r & 7) << 4);
      *(short8*)((char*)q2 + byt) = qo;
      *(short8*)((char*)k2 + byt) = ko;
      *(short8*)((char*)v2 + byt) = v8;
    }
    __syncthreads();  // B1
    {  // pass 2: transpose k2 -> kt2, v2 -> vt2
      int trow = tid >> 1, sh = (tid & 1) * 8;
      short8 tk, tv;
#pragma unroll
      for (int ss = 0; ss < 8; ss++) {
        int s = sh + ss;
        int eidx = ((s * 256 + trow * 2) ^ ((s & 7) << 4)) >> 1;
        tk[ss] = k2[eidx];
        tv[ss] = v2[eidx];
      }
      *(short8*)(kt2 + trow * 24 + sh) = tk;
      *(short8*)(vt2 + trow * 24 + sh) = tv;
    }
    // scores: only wave0 computes & publishes masked bf16 P; all waves load aq
    short8 aq[4];
#pragma unroll
    for (int kk = 0; kk < 4; kk++) {
      int byt = (ll * 256 + (kk * 32 + lh * 8) * 2) ^ ((ll & 7) << 4);
      aq[kk] = *(const short8*)((char*)q2 + byt);
    }
    if (wid == 0) {
      f32x4 sc = {0.f, 0.f, 0.f, 0.f};
#pragma unroll
      for (int kk = 0; kk < 4; kk++) {
        int byt = (ll * 256 + (kk * 32 + lh * 8) * 2) ^ ((ll & 7) << 4);
        short8 bk = *(const short8*)((char*)k2 + byt);
        sc = MFMA16x16x32(aq[kk], bk, sc, 0, 0, 0);
      }
#pragma unroll
      for (int j = 0; j < 4; j++) {
        int t = lh * 4 + j;
        p2[t * 24 + ll] = f2bf_rn((ll <= t) ? sc[j] : 0.f);
      }
    }
    // mirror state (entering this sub-block) to st_lds as bf16
#pragma unroll
    for (int tm = 0; tm < 8; tm++)
#pragma unroll
      for (int tn = 0; tn < 2; tn++) {
        int dv = (2 * wid + tn) * 16 + ll;
        int dkb = tm * 16 + lh * 4;
        short4v pk;
#pragma unroll
        for (int j = 0; j < 4; j++) pk[j] = f2bf_rn(acc[tm][tn][j]);
        *(short4v*)((char*)st_lds + ((dv * 256 + dkb * 2) ^ ((dv & 7) << 4))) = pk;
      }
    __syncthreads();  // B2
    {  // o = q' * S + P V (MFMA), write rows to o_lds
      f32x4 oa0 = {0.f, 0.f, 0.f, 0.f}, oa1 = {0.f, 0.f, 0.f, 0.f};
      int dv0 = (2 * wid) * 16 + ll, dv1 = (2 * wid + 1) * 16 + ll;
#pragma unroll
      for (int kk = 0; kk < 4; kk++) {
        int co = (kk * 32 + lh * 8) * 2;
        short8 bs0 = *(const short8*)((char*)st_lds + ((dv0 * 256 + co) ^ ((dv0 & 7) << 4)));
        short8 bs1 = *(const short8*)((char*)st_lds + ((dv1 * 256 + co) ^ ((dv1 & 7) << 4)));
        oa0 = MFMA16x16x32(aq[kk], bs0, oa0, 0, 0, 0);
        oa1 = MFMA16x16x32(aq[kk], bs1, oa1, 0, 0, 0);
      }
      short8 ap = (short8){0, 0, 0, 0, 0, 0, 0, 0};
      short8 bv0 = ap, bv1 = ap;
      if (lh < 2) {  // K=16 zero-extended to K=32
        ap = *(const short8*)(p2 + ll * 24 + lh * 8);
        bv0 = *(const short8*)(vt2 + dv0 * 24 + lh * 8);
        bv1 = *(const short8*)(vt2 + dv1 * 24 + lh * 8);
      }
      oa0 = MFMA16x16x32(ap, bv0, oa0, 0, 0, 0);
      oa1 = MFMA16x16x32(ap, bv1, oa1, 0, 0, 0);
#pragma unroll
      for (int j = 0; j < 4; j++) {
        o_lds[(lh * 4 + j) * 136 + dv0] = oa0[j];
        o_lds[(lh * 4 + j) * 136 + dv1] = oa1[j];
      }
    }
    {  // state update: acc = e .* (acc + K''^T V)
      int dv0 = (2 * wid) * 16 + ll, dv1 = (2 * wid + 1) * 16 + ll;
      short8 bv0 = (short8){0, 0, 0, 0, 0, 0, 0, 0}, bv1 = bv0;
      if (lh < 2) {
        bv0 = *(const short8*)(vt2 + dv0 * 24 + lh * 8);
        bv1 = *(const short8*)(vt2 + dv1 * 24 + lh * 8);
      }
#pragma unroll
      for (int tm = 0; tm < 8; tm++) {
        short8 ak = (short8){0, 0, 0, 0, 0, 0, 0, 0};
        if (lh < 2) ak = *(const short8*)(kt2 + (tm * 16 + ll) * 24 + lh * 8);
        acc[tm][0] = MFMA16x16x32(ak, bv0, acc[tm][0], 0, 0, 0);
        acc[tm][1] = MFMA16x16x32(ak, bv1, acc[tm][1], 0, 0, 0);
      }
#pragma unroll
      for (int tm = 0; tm < 8; tm++)
#pragma unroll
        for (int j = 0; j < 4; j++) {
          float e = etot[tm * 16 + lh * 4 + j];  // broadcast read
          acc[tm][0][j] *= e;
          acc[tm][1][j] *= e;
        }
    }
    __syncthreads();  // B3
    {  // epilogue: RMSNorm * gnw * swish(g) -> int8 quant
      f32x4 o0 = *(const f32x4*)(o_lds + t_c * 136 + dvb * 8);
      f32x4 o1 = *(const f32x4*)(o_lds + t_c * 136 + dvb * 8 + 4);
      float ov[8] = {o0.x, o0.y, o0.z, o0.w, o1.x, o1.y, o1.z, o1.w};
      float ssq = 0.f;
#pragma unroll
      for (int j = 0; j < 8; j++) ssq += ov[j] * ov[j];
      red[t_c][dvb] = ssq;
      __syncthreads();  // B4
      float tot = 0.f;
#pragma unroll
      for (int i = 0; i < 16; i++) tot += red[t_c][i];
      float rms = rsqrtf(tot * (1.f / 128.f) + 1e-5f);
      size_t gidx = rowbase + (size_t)(sb * 16 + t_c) * 2048 + dvb * 8;
      short8 g8 = *(const short8*)(Gb + gidx);
      char8 outv;
#pragma unroll
      for (int j = 0; j < 8; j++) {
        float g = bf2f(g8[j]);
        float sw = g / (1.f + __expf(-g));
        float val = ov[j] * rms * gnw[dvb * 8 + j] * sw;
        outv[j] = (char)(int)quant1(val, oas);
      }
      *(char8*)(Oq + gidx) = outv;
    }
  }
}

extern "C" void kernel_launch(void* const* d_in, const int* in_sizes, int n_in,
                              void* d_out, int out_size, void* d_ws, size_t ws_size,
                              hipStream_t stream) {
  const float* x = (const float*)d_in[0];
  const int* qw = (const int*)d_in[1];
  const float* qws = (const float*)d_in[2];
  const float* qas = (const float*)d_in[3];
  const int* kw = (const int*)d_in[4];
  const float* kws = (const float*)d_in[5];
  const float* kas = (const float*)d_in[6];
  const int* vw = (const int*)d_in[7];
  const float* vws = (const float*)d_in[8];
  const float* vas = (const float*)d_in[9];
  const int* gw = (const int*)d_in[10];
  const float* gws = (const float*)d_in[11];
  const float* gas = (const float*)d_in[12];
  const int* ow = (const int*)d_in[13];
  const float* ows = (const float*)d_in[14];
  const float* oas = (const float*)d_in[15];
  const int* gk0w = (const int*)d_in[16];
  const float* gk0ws = (const float*)d_in[17];
  const float* gk0as = (const float*)d_in[18];
  const int* gk1w = (const int*)d_in[19];
  const float* gk1ws = (const float*)d_in[20];
  const float* gk1as = (const float*)d_in[21];
  const float* gk1b = (const float*)d_in[22];
  const float* gnw = (const float*)d_in[23];

  const size_t NEEDED = 234881024ull;  // 224 MiB
  if (ws_size < NEEDED) return;

  char* ws = (char*)d_ws;
  char* WB = ws;
  char* XQq = ws + 16777216ull;
  short* KB = (short*)(ws + 33554432ull);
  short* VB = (short*)(ws + 67108864ull);
  short* GB = (short*)(ws + 100663296ull);
  char* XQk = ws + 134217728ull;
  char* XQv = ws + 150994944ull;
  char* XQg = ws + 167772160ull;
  char* XQgk = ws + 184549376ull;
  float* AB = (float*)(ws + 134217728ull);  // written by gk1 AFTER XQk..XQgk consumed
  short* US = (short*)(ws + 201326592ull);
  float* INNER = (float*)(ws + 201326592ull);
  char* OW = ws + 201326592ull;
  float* CT = (float*)ws;     // 512 KB, reuses dead weight region (phaseA onward)
  short* QB = (short*)d_out;  // q stored bf16, borrowing d_out until phaseC consumes it
  char* OQ = XQq;             // OQ reuses XQq slot (dead after q-GEMM)

  // 1. repack q,k,v,g weights (int32 -> int8), single fused launch
  repack4_kernel<<<1024, 256, 0, stream>>>(qw, kw, vw, gw, WB);

  // 2. fused activation quant (read x once, 5 int8 outputs)
  quant5_kernel<<<2048, 256, 0, stream>>>(x, XQq, XQk, XQv, XQg, XQgk, qas, kas, vas, gas,
                                          gk0as, 2097152);

  // 3. all 4 projection GEMMs in ONE launch (1024 blocks; tail/head overlap)
  gemm4_i8<<<1024, 512, 0, stream>>>(XQq, XQk, XQv, XQg, WB, QB, KB, VB, GB, qws, kws, vws,
                                     gws, qas, kas, vas, gas);

  // 4. gk path: i8-MFMA gk0, then gk1 (RAW log-gates) -> AB
  gk0_kernel<<<128, 256, 0, stream>>>(XQgk, gk0w, gk0ws, gk0as, INNER);
  gk1_kernel<<<1024, 256, 0, stream>>>(INNER, gk1w, gk1ws, gk1as, gk1b, AB);

  // 5. chunked GLA scan (CT overwrites dead q/k/v/g weights)
  phaseA_kernel<<<1024, 256, 0, stream>>>(AB, KB, VB, US, CT);
  phaseB_kernel<<<256, 256, 0, stream>>>(CT, US);
  phaseC_kernel<<<1024, 256, 0, stream>>>(AB, QB, KB, VB, GB, US, gnw, oas, OQ);

  // 6. output projection (OW repacked into dead US region)
  repack_w_kernel<<<1024, 256, 0, stream>>>(ow, OW, 262144);
  gemm_i8<<<256, 512, 0, stream>>>(OQ, OW, (float*)d_out, ows, oas);
}

// Round 22
// 520.591 us; speedup vs baseline: 1.0736x; 1.0512x over previous
//
#include <hip/hip_runtime.h>

typedef __attribute__((ext_vector_type(4))) float f32x4;
typedef __attribute__((ext_vector_type(8))) short short8;
typedef __attribute__((ext_vector_type(4))) short short4v;
typedef __attribute__((ext_vector_type(4))) int int4v;
typedef __attribute__((ext_vector_type(8))) char char8;
typedef __attribute__((ext_vector_type(16))) char char16;
typedef unsigned int uint32;

#define DEVFN static __device__ __forceinline__
#define MFMA16x16x32 __builtin_amdgcn_mfma_f32_16x16x32_bf16
#define MFMA_I8 __builtin_amdgcn_mfma_i32_16x16x64_i8

DEVFN short f2bf_rn(float f) {  // round-to-nearest-even f32->bf16 (exact for small ints)
  uint32 u = __float_as_uint(f);
  u += 0x7FFFu + ((u >> 16) & 1u);
  return (short)(u >> 16);
}
DEVFN float bf2f(short s) { return __uint_as_float(((uint32)(unsigned short)s) << 16); }
DEVFN float quant1(float v, float as) {  // int8 symmetric quant (round-half-even like jnp.round)
  return fminf(fmaxf(rintf(v / as), -128.f), 127.f);
}
DEVFN void store1(float* p, float v) { *p = v; }
DEVFN void store1(short* p, float v) { *p = f2bf_rn(v); }

DEVFN void gload_lds16(const void* g, void* l) {  // async global->LDS, 16B/lane
  __builtin_amdgcn_global_load_lds((const __attribute__((address_space(1))) void*)g,
                                   (__attribute__((address_space(3))) void*)l, 16, 0, 0);
}

// ---------------- weight repack x4: int32 (|w|<=8) -> int8, one launch ----------------
__global__ __launch_bounds__(256) void repack4_kernel(const int* __restrict__ w0,
                                                      const int* __restrict__ w1,
                                                      const int* __restrict__ w2,
                                                      const int* __restrict__ w3,
                                                      char* __restrict__ wq) {
  int which = blockIdx.x >> 8;  // 1024 blocks = 4 weights x 256 blocks
  const int* w = which == 0 ? w0 : which == 1 ? w1 : which == 2 ? w2 : w3;
  char* dst = wq + (size_t)which * 4194304;
  int base = (blockIdx.x & 255) * 1024;  // char16 units; 262144 per weight
  for (int it = 0; it < 4; it++) {
    int i = base + it * 256 + threadIdx.x;
    char16 o;
#pragma unroll
    for (int s = 0; s < 4; s++) {
      int4v v = ((const int4v*)w)[i * 4 + s];
#pragma unroll
      for (int j = 0; j < 4; j++) o[s * 4 + j] = (char)v[j];
    }
    ((char16*)dst)[i] = o;
  }
}

// ---------------- weight repack: int32 (|w|<=8) -> int8 (single) ----------------
__global__ __launch_bounds__(256) void repack_w_kernel(const int* __restrict__ w,
                                                       char* __restrict__ wq, int n16) {
  int stride = gridDim.x * blockDim.x;
  for (int i = blockIdx.x * blockDim.x + threadIdx.x; i < n16; i += stride) {
    char16 o;
#pragma unroll
    for (int s = 0; s < 4; s++) {
      int4v v = ((const int4v*)w)[i * 4 + s];
#pragma unroll
      for (int j = 0; j < 4; j++) o[s * 4 + j] = (char)v[j];
    }
    ((char16*)wq)[i] = o;
  }
}

// ------- fused activation quantize: read x once, emit all 5 int8 quantizations -------
__global__ __launch_bounds__(256) void quant5_kernel(
    const float* __restrict__ x, char* __restrict__ o_q, char* __restrict__ o_k,
    char* __restrict__ o_v, char* __restrict__ o_g, char* __restrict__ o_gk,
    const float* __restrict__ as_q, const float* __restrict__ as_k,
    const float* __restrict__ as_v, const float* __restrict__ as_g,
    const float* __restrict__ as_gk, int n8) {
  float aq = as_q[0], ak = as_k[0], av = as_v[0], ag = as_g[0], agk = as_gk[0];
  int stride = gridDim.x * blockDim.x;
  for (int i = blockIdx.x * blockDim.x + threadIdx.x; i < n8; i += stride) {
    f32x4 a = ((const f32x4*)x)[i * 2];
    f32x4 b = ((const f32x4*)x)[i * 2 + 1];
    float v[8] = {a.x, a.y, a.z, a.w, b.x, b.y, b.z, b.w};
    char8 q8, k8, v8, g8, gk8;
#pragma unroll
    for (int j = 0; j < 8; j++) {
      q8[j] = (char)(int)quant1(v[j], aq);
      k8[j] = (char)(int)quant1(v[j], ak);
      v8[j] = (char)(int)quant1(v[j], av);
      g8[j] = (char)(int)quant1(v[j], ag);
      gk8[j] = (char)(int)quant1(v[j], agk);
    }
    ((char8*)o_q)[i] = q8;
    ((char8*)o_k)[i] = k8;
    ((char8*)o_v)[i] = v8;
    ((char8*)o_g)[i] = g8;
    ((char8*)o_gk)[i] = gk8;
  }
}

// ---- i8 MFMA GEMM v3 (proven best): 256^2 tile, depth-2 counted-vmcnt (T4), setprio (T5) ----
template <typename OutT>
__global__ __launch_bounds__(512, 2) void gemm_i8(const char* __restrict__ A,
                                                  const char* __restrict__ W,
                                                  OutT* __restrict__ C,
                                                  const float* __restrict__ wscale,
                                                  const float* __restrict__ ascale_p) {
  const int K = 2048, N = 2048, NT = 32;
  int wg = blockIdx.x;                  // 256 blocks = 32 bm x 8 bn, 1 per CU
  int swz = (wg & 7) * 32 + (wg >> 3);  // XCD swizzle, bijective (256 % 8 == 0)
  int bm = swz >> 3, bn = swz & 7;

  __shared__ char As[2][256 * 64] __attribute__((aligned(16)));
  __shared__ char Bs[2][256 * 64] __attribute__((aligned(16)));

  int tid = threadIdx.x, lane = tid & 63, wid = tid >> 6;
  int wr = wid >> 2, wc = wid & 3;  // wave grid 2x4 -> 128x64 output per wave
  int ll = lane & 15, lh = lane >> 4;

  int4v acc[8][4];
#pragma unroll
  for (int m = 0; m < 8; m++)
#pragma unroll
    for (int n = 0; n < 4; n++) acc[m][n] = (int4v){0, 0, 0, 0};

  const char* Abase = A + (size_t)(bm * 256) * K;
  const char* Wbase = W + (size_t)(bn * 256) * K;

#define STAGE(buf, kt)                                                                   \
  {                                                                                      \
    _Pragma("unroll") for (int i = 0; i < 2; i++) {                                      \
      int rr = i * 128 + (tid >> 2);                                                     \
      int scc = (tid & 3) ^ ((rr >> 1) & 3);                                             \
      int ub = (i * 512 + wid * 64) * 16;                                                \
      gload_lds16(Abase + (size_t)rr * K + (kt) * 64 + scc * 16, (char*)As[buf] + ub);   \
      gload_lds16(Wbase + (size_t)rr * K + (kt) * 64 + scc * 16, (char*)Bs[buf] + ub);   \
    }                                                                                    \
  }

  STAGE(0, 0);
  STAGE(1, 1);  // depth-2 prologue: 8 loads/thread in flight
  int cur = 0;
  for (int kt = 0; kt < NT; kt++) {
    if (kt < NT - 1)
      asm volatile("s_waitcnt vmcnt(4)" ::: "memory");
    else
      asm volatile("s_waitcnt vmcnt(0)" ::: "memory");
    __builtin_amdgcn_s_barrier();
    asm volatile("" ::: "memory");  // keep ds_reads below the barrier
    int4v af[8], bfv[4];
#pragma unroll
    for (int m = 0; m < 8; m++) {
      int row = wr * 128 + m * 16 + ll;
      af[m] = *(const int4v*)(As[cur] + row * 64 + ((lh ^ ((row >> 1) & 3)) * 16));
    }
#pragma unroll
    for (int n = 0; n < 4; n++) {
      int row = wc * 64 + n * 16 + ll;
      bfv[n] = *(const int4v*)(Bs[cur] + row * 64 + ((lh ^ ((row >> 1) & 3)) * 16));
    }
    __builtin_amdgcn_s_setprio(1);
#pragma unroll
    for (int m = 0; m < 8; m++)
#pragma unroll
      for (int n = 0; n < 4; n++) acc[m][n] = MFMA_I8(af[m], bfv[n], acc[m][n], 0, 0, 0);
    __builtin_amdgcn_s_setprio(0);
    asm volatile("" ::: "memory");  // keep ds_reads above the barrier
    __builtin_amdgcn_s_barrier();   // read-done: buffer may now be overwritten
    if (kt + 2 < NT) STAGE(cur, kt + 2);
    cur ^= 1;
  }
  float as = ascale_p[0];
#pragma unroll
  for (int n = 0; n < 4; n++) {
    int col = bn * 256 + wc * 64 + n * 16 + ll;
    float sc = as * wscale[col];
#pragma unroll
    for (int m = 0; m < 8; m++) {
      int r0 = bm * 256 + wr * 128 + m * 16 + lh * 4;
#pragma unroll
      for (int j = 0; j < 4; j++) store1(C + (size_t)(r0 + j) * N + col, (float)acc[m][n][j] * sc);
    }
  }
#undef STAGE
}

// ---- gk0 (v2, MFMA): inner[8192][16] = gk0as*w0s[n] * XQ[8192][2048]i8 x W0[16][2048]^T ----
__global__ __launch_bounds__(256) void gk0_kernel(const char* __restrict__ xq,
                                                  const int* __restrict__ w0,
                                                  const float* __restrict__ w0s,
                                                  const float* __restrict__ as_p,
                                                  float* __restrict__ inner) {
  const int K = 2048;
  __shared__ char W8[16 * 2064] __attribute__((aligned(16)));  // [n][k] int8, pitch 2064
  __shared__ char As[2][64 * 64] __attribute__((aligned(16)));

  int tid = threadIdx.x, lane = tid & 63, wid = tid >> 6;
  int ll = lane & 15, lh = lane >> 4;
  int bm = blockIdx.x;  // 128 blocks x 64 rows

#pragma unroll
  for (int i = 0; i < 32; i++) {
    int idx = i * 256 + tid;  // int4v index (8192 total)
    int4v v = ((const int4v*)w0)[idx];
    int e = idx * 4;
    char* p = W8 + (e >> 11) * 2064 + (e & 2047);
    p[0] = (char)v.x;
    p[1] = (char)v.y;
    p[2] = (char)v.z;
    p[3] = (char)v.w;
  }

  const char* Abase = xq + (size_t)(bm * 64) * K;
#define STAGEA(buf, kt)                                                              \
  {                                                                                  \
    int rr = tid >> 2, cc = tid & 3;                                                 \
    int ub = wid * 64 * 16;                                                          \
    gload_lds16(Abase + (size_t)rr * K + (kt) * 64 + cc * 16, (char*)As[buf] + ub);  \
  }

  int4v acc = (int4v){0, 0, 0, 0};
  STAGEA(0, 0);
  __syncthreads();
  int cur = 0;
  for (int kt = 0; kt < 32; kt++) {
    if (kt + 1 < 32) STAGEA(cur ^ 1, kt + 1);
    int4v bfv = *(const int4v*)(W8 + ll * 2064 + kt * 64 + lh * 16);
    int4v af = *(const int4v*)(As[cur] + (wid * 16 + ll) * 64 + lh * 16);
    acc = MFMA_I8(af, bfv, acc, 0, 0, 0);
    __syncthreads();
    cur ^= 1;
  }
  float sc = as_p[0] * w0s[ll];
  int r0 = bm * 64 + wid * 16 + lh * 4;
#pragma unroll
  for (int j = 0; j < 4; j++) inner[(size_t)(r0 + j) * 16 + ll] = (float)acc[j] * sc;
#undef STAGEA
}

// -- gk1 (v2): AB = log_sigmoid(qlinear(inner, gk1)+bias)/16 via native exp/log, f32x4 dots --
__global__ __launch_bounds__(256) void gk1_kernel(const float* __restrict__ inner,
                                                  const int* __restrict__ w1,
                                                  const float* __restrict__ w1s,
                                                  const float* __restrict__ as_p,
                                                  const float* __restrict__ bias,
                                                  float* __restrict__ glog) {
  __shared__ float xq1[8][16] __attribute__((aligned(16)));
  float as = as_p[0];
  int tid = threadIdx.x;
  int m0 = blockIdx.x * 8;
  if (tid < 128) {
    int t = tid >> 4, n = tid & 15;
    xq1[t][n] = quant1(inner[(size_t)(m0 + t) * 16 + n], as);
  }
  __syncthreads();
#pragma unroll
  for (int i = 0; i < 8; i++) {
    int j = tid + i * 256;
    const int* wr = w1 + (size_t)j * 16;
    f32x4 wv[4];
#pragma unroll
    for (int n4 = 0; n4 < 4; n4++) {
      int4v wi = *(const int4v*)(wr + n4 * 4);
      wv[n4] = (f32x4){(float)wi.x, (float)wi.y, (float)wi.z, (float)wi.w};
    }
    float sc = as * w1s[j];
    float bj = bias[j];
#pragma unroll
    for (int t = 0; t < 8; t++) {
      f32x4 a4 = {0.f, 0.f, 0.f, 0.f};
#pragma unroll
      for (int n4 = 0; n4 < 4; n4++) a4 += *(const f32x4*)&xq1[t][n4 * 4] * wv[n4];
      float raw = (a4.x + a4.y + a4.z + a4.w) * sc + bj;
      float y = __expf(-fabsf(raw));
      float ls = fminf(raw, 0.f) - __logf(1.f + y);
      glog[(size_t)(m0 + t) * 2048 + j] = ls * 0.0625f;
    }
  }
}

// ------- phase A (v3, MFMA): RAW gates, LDS prefix; U = e^{atot}(U + K''^T V) recurrence ---
__global__ __launch_bounds__(256) void phaseA_kernel(const float* __restrict__ Abuf,
                                                     const short* __restrict__ Kb,
                                                     const short* __restrict__ Vb,
                                                     short* __restrict__ U,
                                                     float* __restrict__ CT) {
  __shared__ short k2[16 * 128] __attribute__((aligned(16)));   // [s][dk], swizzled
  __shared__ short v2[16 * 128] __attribute__((aligned(16)));   // [s][dv], swizzled
  __shared__ short kt2[128 * 24] __attribute__((aligned(16)));  // [dk][s], pitch 24
  __shared__ short vt2[128 * 24] __attribute__((aligned(16)));  // [dv][s], pitch 24
  __shared__ float a_lds[16 * 136] __attribute__((aligned(16)));
  __shared__ float etot[128];

  int cid = blockIdx.x;  // [b][h][c]
  int bb = cid >> 9, h = (cid >> 5) & 15, c = cid & 31;
  size_t rowbase = ((size_t)bb * 4096 + (size_t)c * 128) * 2048 + h * 128;
  int tid = threadIdx.x, lane = tid & 63, wid = tid >> 6;
  int lh = lane >> 4, ll = lane & 15;
  int r = tid >> 4, d0 = (tid & 15) * 8;

  f32x4 acc[8][2];
#pragma unroll
  for (int tm = 0; tm < 8; tm++) {
    acc[tm][0] = (f32x4){0.f, 0.f, 0.f, 0.f};
    acc[tm][1] = (f32x4){0.f, 0.f, 0.f, 0.f};
  }
  float ct[8] = {0.f, 0.f, 0.f, 0.f, 0.f, 0.f, 0.f, 0.f};  // valid on r==15 threads

  for (int sb = 0; sb < 8; sb++) {
    __syncthreads();  // A0
    size_t ridx = rowbase + (size_t)(sb * 16 + r) * 2048 + d0;
    short8 k8 = *(const short8*)(Kb + ridx);
    short8 v8 = *(const short8*)(Vb + ridx);
    {
      f32x4 a0 = *(const f32x4*)(Abuf + ridx);
      f32x4 a1 = *(const f32x4*)(Abuf + ridx + 4);
      *(f32x4*)(a_lds + r * 136 + d0) = a0;
      *(f32x4*)(a_lds + r * 136 + d0 + 4) = a1;
    }
    __syncthreads();  // A1
    if (tid < 128) {  // per-column inclusive prefix over 16 rows
      int d = tid;
      float s = 0.f;
#pragma unroll
      for (int rr = 0; rr < 16; rr++) {
        s += a_lds[rr * 136 + d];
        a_lds[rr * 136 + d] = s;
      }
    }
    __syncthreads();  // A2
    {  // k'' = k * e^{-arel}; stage swizzled; r==15 tracks etot + chunk-total logs
      short8 ko;
#pragma unroll
      for (int j = 0; j < 8; j++) {
        float arel = a_lds[r * 136 + d0 + j];
        ko[j] = f2bf_rn(bf2f(k8[j]) * __expf(-arel));
        if (r == 15) {
          etot[d0 + j] = __expf(arel);
          ct[j] += arel;
        }
      }
      int byt = (r * 256 + d0 * 2) ^ ((r & 7) << 4);
      *(short8*)((char*)k2 + byt) = ko;
      *(short8*)((char*)v2 + byt) = v8;
    }
    __syncthreads();  // A3
    {  // transpose k2 -> kt2, v2 -> vt2
      int trow = tid >> 1, sh = (tid & 1) * 8;
      short8 tk, tv;
#pragma unroll
      for (int ss = 0; ss < 8; ss++) {
        int s = sh + ss;
        int eidx = ((s * 256 + trow * 2) ^ ((s & 7) << 4)) >> 1;
        tk[ss] = k2[eidx];
        tv[ss] = v2[eidx];
      }
      *(short8*)(kt2 + trow * 24 + sh) = tk;
      *(short8*)(vt2 + trow * 24 + sh) = tv;
    }
    __syncthreads();  // A4
    {  // U-acc update: acc = e^{atot} .* (acc + K''^T V)  (K=16 zero-extended)
      int dv0 = (2 * wid) * 16 + ll, dv1 = (2 * wid + 1) * 16 + ll;
      short8 bv0 = (short8){0, 0, 0, 0, 0, 0, 0, 0}, bv1 = bv0;
      if (lh < 2) {
        bv0 = *(const short8*)(vt2 + dv0 * 24 + lh * 8);
        bv1 = *(const short8*)(vt2 + dv1 * 24 + lh * 8);
      }
#pragma unroll
      for (int tm = 0; tm < 8; tm++) {
        short8 ak = (short8){0, 0, 0, 0, 0, 0, 0, 0};
        if (lh < 2) ak = *(const short8*)(kt2 + (tm * 16 + ll) * 24 + lh * 8);
        acc[tm][0] = MFMA16x16x32(ak, bv0, acc[tm][0], 0, 0, 0);
        acc[tm][1] = MFMA16x16x32(ak, bv1, acc[tm][1], 0, 0, 0);
      }
#pragma unroll
      for (int tm = 0; tm < 8; tm++)
#pragma unroll
        for (int j = 0; j < 4; j++) {
          float e = etot[tm * 16 + lh * 4 + j];
          acc[tm][0][j] *= e;
          acc[tm][1][j] *= e;
        }
    }
  }
  // write U as bf16 [dv][dk] (short4v fragments: 4 consecutive dk per reg group)
  size_t ub = (size_t)cid * 16384;
#pragma unroll
  for (int tm = 0; tm < 8; tm++)
#pragma unroll
    for (int tn = 0; tn < 2; tn++) {
      int dv = (2 * wid + tn) * 16 + ll;
      short4v o;
#pragma unroll
      for (int j = 0; j < 4; j++) o[j] = f2bf_rn(acc[tm][tn][j]);
      *(short4v*)(U + ub + (size_t)dv * 128 + tm * 16 + lh * 4) = o;
    }
  if (r == 15) {
#pragma unroll
    for (int j = 0; j < 8; j++) CT[(size_t)cid * 128 + d0 + j] = ct[j];
  }
}

// ------- phase B: sequential inter-chunk recurrence, U->S in place ([dv][dk] bf16) -------
__global__ __launch_bounds__(256) void phaseB_kernel(const float* __restrict__ CT,
                                                     short* __restrict__ US) {
  int bid = blockIdx.x;  // [b][h][dvb]
  int bb = bid >> 7, h = (bid >> 3) & 15, dvb = bid & 7;
  int tid = threadIdx.x;
  int dv = dvb * 16 + (tid >> 4);
  int dk0 = (tid & 15) * 8;
  f32x4 s0 = {0.f, 0.f, 0.f, 0.f}, s1 = {0.f, 0.f, 0.f, 0.f};
  size_t tb = (size_t)((bb * 16 + h) * 32) * 16384 + (size_t)dv * 128 + dk0;
  size_t ctb = (size_t)((bb * 16 + h) * 32) * 128 + dk0;
  for (int c = 0; c < 32; c++) {
    size_t off = tb + (size_t)c * 16384;
    short8 u8 = *(const short8*)(US + off);  // load U BEFORE overwrite
    f32x4 ea = *(const f32x4*)(CT + ctb + (size_t)c * 128);
    f32x4 eb = *(const f32x4*)(CT + ctb + (size_t)c * 128 + 4);
    short8 st;
    st[0] = f2bf_rn(s0.x); st[1] = f2bf_rn(s0.y); st[2] = f2bf_rn(s0.z); st[3] = f2bf_rn(s0.w);
    st[4] = f2bf_rn(s1.x); st[5] = f2bf_rn(s1.y); st[6] = f2bf_rn(s1.z); st[7] = f2bf_rn(s1.w);
    *(short8*)(US + off) = st;  // state ENTERING chunk c
#pragma unroll
    for (int j = 0; j < 4; j++) {
      s0[j] = __expf(ea[j]) * s0[j] + bf2f(u8[j]);
      s1[j] = __expf(eb[j]) * s1[j] + bf2f(u8[4 + j]);
    }
  }
}

// --- phase C (R17-proven shape: RAW gates + LDS prefix; Qb bf16) ---
__global__ __launch_bounds__(256) void phaseC_kernel(
    const float* __restrict__ Abuf, const short* __restrict__ Qb, const short* __restrict__ Kb,
    const short* __restrict__ Vb, const short* __restrict__ Gb, const short* __restrict__ S,
    const float* __restrict__ gnw, const float* __restrict__ oas_p, char* __restrict__ Oq) {
  __shared__ short st_lds[128 * 128] __attribute__((aligned(16)));  // [dv][dk], byte^((dv&7)<<4)
  __shared__ short q2[16 * 128] __attribute__((aligned(16)));       // [t][dk], byte^((t&7)<<4)
  __shared__ short k2[16 * 128] __attribute__((aligned(16)));       // [s][dk], swz
  __shared__ short v2[16 * 128] __attribute__((aligned(16)));       // [s][dv], swz
  __shared__ short kt2[128 * 24] __attribute__((aligned(16)));      // [dk][s], pitch 24
  __shared__ short vt2[128 * 24] __attribute__((aligned(16)));      // [dv][s], pitch 24
  __shared__ short p2[16 * 24] __attribute__((aligned(16)));        // [t][s], pitch 24
  __shared__ float etot[128];
  __shared__ float o_lds[16 * 136] __attribute__((aligned(16)));    // a_raw -> arel -> o rows
  __shared__ float red[16][17];

  int cid = blockIdx.x;
  int bb = cid >> 9, h = (cid >> 5) & 15, c = cid & 31;
  size_t rowbase = ((size_t)bb * 4096 + (size_t)c * 128) * 2048 + h * 128;
  int tid = threadIdx.x, lane = tid & 63, wid = tid >> 6;
  int lh = lane >> 4, ll = lane & 15;
  float oas = oas_p[0];

  // ---- init state accumulators from S (bf16 [dv][dk] global, short4v fragments) ----
  f32x4 acc[8][2];
  {
    size_t sb0 = (size_t)cid * 16384;
#pragma unroll
    for (int tm = 0; tm < 8; tm++)
#pragma unroll
      for (int tn = 0; tn < 2; tn++) {
        int dv = (2 * wid + tn) * 16 + ll;
        short4v s4 = *(const short4v*)(S + sb0 + (size_t)dv * 128 + tm * 16 + lh * 4);
        f32x4 a;
#pragma unroll
        for (int j = 0; j < 4; j++) a[j] = bf2f(s4[j]);
        acc[tm][tn] = a;
      }
  }

  int r = tid >> 4, d0 = (tid & 15) * 8;  // staging mapping
  int t_c = tid & 15, dvb = tid >> 4;     // epilogue mapping

  for (int sb = 0; sb < 8; sb++) {
    __syncthreads();  // B0
    // pass 1a: load raw a -> o_lds(a_raw); hold q,k,v in registers (q bf16)
    size_t ridx = rowbase + (size_t)(sb * 16 + r) * 2048 + d0;
    short8 q8 = *(const short8*)(Qb + ridx);
    short8 k8 = *(const short8*)(Kb + ridx);
    short8 v8 = *(const short8*)(Vb + ridx);
    {
      f32x4 a0 = *(const f32x4*)(Abuf + ridx);
      f32x4 a1 = *(const f32x4*)(Abuf + ridx + 4);
      *(f32x4*)(o_lds + r * 136 + d0) = a0;
      *(f32x4*)(o_lds + r * 136 + d0 + 4) = a1;
    }
    __syncthreads();  // B0b
    if (tid < 128) {  // per-column inclusive prefix over the 16 staged rows
      int d = tid;
      float s = 0.f;
#pragma unroll
      for (int rr = 0; rr < 16; rr++) {
        s += o_lds[rr * 136 + d];
        o_lds[rr * 136 + d] = s;
      }
    }
    __syncthreads();  // B0c
    {  // pass 1b: scale q/k by decays, write swizzled q2/k2/v2, etot
      short8 qo, ko;
#pragma unroll
      for (int j = 0; j < 8; j++) {
        float arel = o_lds[r * 136 + d0 + j];  // inclusive local prefix, <= 0
        float ep = __expf(arel);
        qo[j] = f2bf_rn(bf2f(q8[j]) * 0.08838834764831843f * ep);
        ko[j] = f2bf_rn(bf2f(k8[j]) * __expf(-arel));
        if (r == 15) etot[d0 + j] = ep;
      }
      int byt = (r * 256 + d0 * 2) ^ ((r & 7) << 4);
      *(short8*)((char*)q2 + byt) = qo;
      *(short8*)((char*)k2 + byt) = ko;
      *(short8*)((char*)v2 + byt) = v8;
    }
    __syncthreads();  // B1
    {  // pass 2: transpose k2 -> kt2, v2 -> vt2
      int trow = tid >> 1, sh = (tid & 1) * 8;
      short8 tk, tv;
#pragma unroll
      for (int ss = 0; ss < 8; ss++) {
        int s = sh + ss;
        int eidx = ((s * 256 + trow * 2) ^ ((s & 7) << 4)) >> 1;
        tk[ss] = k2[eidx];
        tv[ss] = v2[eidx];
      }
      *(short8*)(kt2 + trow * 24 + sh) = tk;
      *(short8*)(vt2 + trow * 24 + sh) = tv;
    }
    // scores: only wave0 computes & publishes masked bf16 P; all waves load aq
    short8 aq[4];
#pragma unroll
    for (int kk = 0; kk < 4; kk++) {
      int byt = (ll * 256 + (kk * 32 + lh * 8) * 2) ^ ((ll & 7) << 4);
      aq[kk] = *(const short8*)((char*)q2 + byt);
    }
    if (wid == 0) {
      f32x4 sc = {0.f, 0.f, 0.f, 0.f};
#pragma unroll
      for (int kk = 0; kk < 4; kk++) {
        int byt = (ll * 256 + (kk * 32 + lh * 8) * 2) ^ ((ll & 7) << 4);
        short8 bk = *(const short8*)((char*)k2 + byt);
        sc = MFMA16x16x32(aq[kk], bk, sc, 0, 0, 0);
      }
#pragma unroll
      for (int j = 0; j < 4; j++) {
        int t = lh * 4 + j;
        p2[t * 24 + ll] = f2bf_rn((ll <= t) ? sc[j] : 0.f);
      }
    }
    // mirror state (entering this sub-block) to st_lds as bf16
#pragma unroll
    for (int tm = 0; tm < 8; tm++)
#pragma unroll
      for (int tn = 0; tn < 2; tn++) {
        int dv = (2 * wid + tn) * 16 + ll;
        int dkb = tm * 16 + lh * 4;
        short4v pk;
#pragma unroll
        for (int j = 0; j < 4; j++) pk[j] = f2bf_rn(acc[tm][tn][j]);
        *(short4v*)((char*)st_lds + ((dv * 256 + dkb * 2) ^ ((dv & 7) << 4))) = pk;
      }
    __syncthreads();  // B2
    {  // o = q' * S + P V (MFMA), write rows to o_lds
      f32x4 oa0 = {0.f, 0.f, 0.f, 0.f}, oa1 = {0.f, 0.f, 0.f, 0.f};
      int dv0 = (2 * wid) * 16 + ll, dv1 = (2 * wid + 1) * 16 + ll;
#pragma unroll
      for (int kk = 0; kk < 4; kk++) {
        int co = (kk * 32 + lh * 8) * 2;
        short8 bs0 = *(const short8*)((char*)st_lds + ((dv0 * 256 + co) ^ ((dv0 & 7) << 4)));
        short8 bs1 = *(const short8*)((char*)st_lds + ((dv1 * 256 + co) ^ ((dv1 & 7) << 4)));
        oa0 = MFMA16x16x32(aq[kk], bs0, oa0, 0, 0, 0);
        oa1 = MFMA16x16x32(aq[kk], bs1, oa1, 0, 0, 0);
      }
      short8 ap = (short8){0, 0, 0, 0, 0, 0, 0, 0};
      short8 bv0 = ap, bv1 = ap;
      if (lh < 2) {  // K=16 zero-extended to K=32
        ap = *(const short8*)(p2 + ll * 24 + lh * 8);
        bv0 = *(const short8*)(vt2 + dv0 * 24 + lh * 8);
        bv1 = *(const short8*)(vt2 + dv1 * 24 + lh * 8);
      }
      oa0 = MFMA16x16x32(ap, bv0, oa0, 0, 0, 0);
      oa1 = MFMA16x16x32(ap, bv1, oa1, 0, 0, 0);
#pragma unroll
      for (int j = 0; j < 4; j++) {
        o_lds[(lh * 4 + j) * 136 + dv0] = oa0[j];
        o_lds[(lh * 4 + j) * 136 + dv1] = oa1[j];
      }
    }
    {  // state update: acc = e .* (acc + K''^T V)
      int dv0 = (2 * wid) * 16 + ll, dv1 = (2 * wid + 1) * 16 + ll;
      short8 bv0 = (short8){0, 0, 0, 0, 0, 0, 0, 0}, bv1 = bv0;
      if (lh < 2) {
        bv0 = *(const short8*)(vt2 + dv0 * 24 + lh * 8);
        bv1 = *(const short8*)(vt2 + dv1 * 24 + lh * 8);
      }
#pragma unroll
      for (int tm = 0; tm < 8; tm++) {
        short8 ak = (short8){0, 0, 0, 0, 0, 0, 0, 0};
        if (lh < 2) ak = *(const short8*)(kt2 + (tm * 16 + ll) * 24 + lh * 8);
        acc[tm][0] = MFMA16x16x32(ak, bv0, acc[tm][0], 0, 0, 0);
        acc[tm][1] = MFMA16x16x32(ak, bv1, acc[tm][1], 0, 0, 0);
      }
#pragma unroll
      for (int tm = 0; tm < 8; tm++)
#pragma unroll
        for (int j = 0; j < 4; j++) {
          float e = etot[tm * 16 + lh * 4 + j];  // broadcast read
          acc[tm][0][j] *= e;
          acc[tm][1][j] *= e;
        }
    }
    __syncthreads();  // B3
    {  // epilogue: RMSNorm * gnw * swish(g) -> int8 quant
      f32x4 o0 = *(const f32x4*)(o_lds + t_c * 136 + dvb * 8);
      f32x4 o1 = *(const f32x4*)(o_lds + t_c * 136 + dvb * 8 + 4);
      float ov[8] = {o0.x, o0.y, o0.z, o0.w, o1.x, o1.y, o1.z, o1.w};
      float ssq = 0.f;
#pragma unroll
      for (int j = 0; j < 8; j++) ssq += ov[j] * ov[j];
      red[t_c][dvb] = ssq;
      __syncthreads();  // B4
      float tot = 0.f;
#pragma unroll
      for (int i = 0; i < 16; i++) tot += red[t_c][i];
      float rms = rsqrtf(tot * (1.f / 128.f) + 1e-5f);
      size_t gidx = rowbase + (size_t)(sb * 16 + t_c) * 2048 + dvb * 8;
      short8 g8 = *(const short8*)(Gb + gidx);
      char8 outv;
#pragma unroll
      for (int j = 0; j < 8; j++) {
        float g = bf2f(g8[j]);
        float sw = g / (1.f + __expf(-g));
        float val = ov[j] * rms * gnw[dvb * 8 + j] * sw;
        outv[j] = (char)(int)quant1(val, oas);
      }
      *(char8*)(Oq + gidx) = outv;
    }
  }
}

extern "C" void kernel_launch(void* const* d_in, const int* in_sizes, int n_in,
                              void* d_out, int out_size, void* d_ws, size_t ws_size,
                              hipStream_t stream) {
  const float* x = (const float*)d_in[0];
  const int* qw = (const int*)d_in[1];
  const float* qws = (const float*)d_in[2];
  const float* qas = (const float*)d_in[3];
  const int* kw = (const int*)d_in[4];
  const float* kws = (const float*)d_in[5];
  const float* kas = (const float*)d_in[6];
  const int* vw = (const int*)d_in[7];
  const float* vws = (const float*)d_in[8];
  const float* vas = (const float*)d_in[9];
  const int* gw = (const int*)d_in[10];
  const float* gws = (const float*)d_in[11];
  const float* gas = (const float*)d_in[12];
  const int* ow = (const int*)d_in[13];
  const float* ows = (const float*)d_in[14];
  const float* oas = (const float*)d_in[15];
  const int* gk0w = (const int*)d_in[16];
  const float* gk0ws = (const float*)d_in[17];
  const float* gk0as = (const float*)d_in[18];
  const int* gk1w = (const int*)d_in[19];
  const float* gk1ws = (const float*)d_in[20];
  const float* gk1as = (const float*)d_in[21];
  const float* gk1b = (const float*)d_in[22];
  const float* gnw = (const float*)d_in[23];

  const size_t NEEDED = 234881024ull;  // 224 MiB
  if (ws_size < NEEDED) return;

  char* ws = (char*)d_ws;
  char* WB = ws;
  char* XQq = ws + 16777216ull;
  short* KB = (short*)(ws + 33554432ull);
  short* VB = (short*)(ws + 67108864ull);
  short* GB = (short*)(ws + 100663296ull);
  char* XQk = ws + 134217728ull;
  char* XQv = ws + 150994944ull;
  char* XQg = ws + 167772160ull;
  char* XQgk = ws + 184549376ull;
  float* AB = (float*)(ws + 134217728ull);  // written by gk1 AFTER XQk..XQgk consumed
  short* US = (short*)(ws + 201326592ull);
  float* INNER = (float*)(ws + 201326592ull);
  char* OW = ws + 201326592ull;
  float* CT = (float*)ws;     // 512 KB, reuses dead weight region (phaseA onward)
  short* QB = (short*)d_out;  // q stored bf16, borrowing d_out until phaseC consumes it
  char* OQ = XQq;             // OQ reuses XQq slot (dead after q-GEMM)

  // 1. repack q,k,v,g weights (int32 -> int8), single fused launch
  repack4_kernel<<<1024, 256, 0, stream>>>(qw, kw, vw, gw, WB);

  // 2. fused activation quant (read x once, 5 int8 outputs)
  quant5_kernel<<<2048, 256, 0, stream>>>(x, XQq, XQk, XQv, XQg, XQgk, qas, kas, vas, gas,
                                          gk0as, 2097152);

  // 3. projections (256^2-tile i8-MFMA GEMMs, counted-vmcnt pipeline); q bf16
  gemm_i8<short><<<256, 512, 0, stream>>>(XQq, WB + 0ull * 4194304, QB, qws, qas);
  gemm_i8<short><<<256, 512, 0, stream>>>(XQk, WB + 1ull * 4194304, KB, kws, kas);
  gemm_i8<short><<<256, 512, 0, stream>>>(XQv, WB + 2ull * 4194304, VB, vws, vas);
  gemm_i8<short><<<256, 512, 0, stream>>>(XQg, WB + 3ull * 4194304, GB, gws, gas);

  // 4. gk path: i8-MFMA gk0, then gk1 (RAW log-gates) -> AB
  gk0_kernel<<<128, 256, 0, stream>>>(XQgk, gk0w, gk0ws, gk0as, INNER);
  gk1_kernel<<<1024, 256, 0, stream>>>(INNER, gk1w, gk1ws, gk1as, gk1b, AB);

  // 5. chunked GLA scan (CT overwrites dead q/k/v/g weights)
  phaseA_kernel<<<1024, 256, 0, stream>>>(AB, KB, VB, US, CT);
  phaseB_kernel<<<256, 256, 0, stream>>>(CT, US);
  phaseC_kernel<<<1024, 256, 0, stream>>>(AB, QB, KB, VB, GB, US, gnw, oas, OQ);

  // 6. output projection (OW repacked into dead US region)
  repack_w_kernel<<<1024, 256, 0, stream>>>(ow, OW, 262144);
  gemm_i8<float><<<256, 512, 0, stream>>>(OQ, OW, (float*)d_out, ows, oas);
}